// Round 1
// baseline (2105.266 us; speedup 1.0000x reference)
//
#include <hip/hip_runtime.h>

#define N_NODESC 50000
#define N_EDGESC 800000
#define DIMC 128
#define NGC 64
#define HDC 32
#define SLOPEF 0.01f
#define EPSF 1e-5f
#define SCALEF 0.17677669529663687f  // 32^-0.5

// ---------------- CSR build ----------------
__global__ __launch_bounds__(256) void count_kernel(const int* __restrict__ ei, int* __restrict__ cnt) {
  int e = blockIdx.x * 256 + threadIdx.x;
  if (e < N_EDGESC) atomicAdd(&cnt[ei[N_EDGESC + e]], 1);
}

__global__ __launch_bounds__(1024) void scan_kernel(const int* __restrict__ cnt, int* __restrict__ rowptr,
                                                    float* __restrict__ inv) {
  __shared__ int sd[1024];
  const int n = N_NODESC;
  const int per = (n + 1023) / 1024;  // 49
  int t = threadIdx.x;
  int lo = t * per, hi = min(lo + per, n);
  int s = 0;
  for (int i = lo; i < hi; ++i) {
    int v = cnt[i];
    inv[i] = rsqrtf((float)v + 1.0f);
    s += v;
  }
  sd[t] = s;
  __syncthreads();
  for (int off = 1; off < 1024; off <<= 1) {
    int tv = (t >= off) ? sd[t - off] : 0;
    __syncthreads();
    sd[t] += tv;
    __syncthreads();
  }
  int run = sd[t] - s;  // exclusive prefix for this thread's range
  for (int i = lo; i < hi; ++i) {
    rowptr[i] = run;
    run += cnt[i];
  }
  if (t == 1023) rowptr[n] = sd[1023];
}

__global__ __launch_bounds__(256) void fill_kernel(const int* __restrict__ ei, const int* __restrict__ rowptr,
                                                   int* __restrict__ fillc, int* __restrict__ csr) {
  int e = blockIdx.x * 256 + threadIdx.x;
  if (e < N_EDGESC) {
    int s = ei[e];
    int d = ei[N_EDGESC + e];
    int pos = rowptr[d] + atomicAdd(&fillc[d], 1);
    csr[pos] = s;
  }
}

// ---------------- encoder GEMM: Y = (X @ W) * inv[row] ----------------
#define GR 64
__global__ __launch_bounds__(128) void gemm_enc(const float* __restrict__ X, const float* __restrict__ W,
                                                const float* __restrict__ inv, float* __restrict__ Y) {
  __shared__ float Ws[DIMC * DIMC];  // 64 KB
  int t = threadIdx.x;
#pragma unroll
  for (int i = 0; i < DIMC * DIMC; i += 512) {
    *(float4*)&Ws[i + t * 4] = *(const float4*)&W[i + t * 4];
  }
  __syncthreads();
  int row0 = blockIdx.x * GR;
  float acc[GR];
#pragma unroll
  for (int r = 0; r < GR; ++r) acc[r] = 0.f;
  bool full = (row0 + GR <= N_NODESC);
  for (int k0 = 0; k0 < DIMC; k0 += 4) {
    float wv0 = Ws[(k0 + 0) * DIMC + t];
    float wv1 = Ws[(k0 + 1) * DIMC + t];
    float wv2 = Ws[(k0 + 2) * DIMC + t];
    float wv3 = Ws[(k0 + 3) * DIMC + t];
    if (full) {
#pragma unroll
      for (int r = 0; r < GR; ++r) {
        const float* xp = X + (size_t)(row0 + r) * DIMC + k0;  // block-uniform -> s_load
        acc[r] += xp[0] * wv0 + xp[1] * wv1 + xp[2] * wv2 + xp[3] * wv3;
      }
    } else {
#pragma unroll
      for (int r = 0; r < GR; ++r) {
        if (row0 + r < N_NODESC) {
          const float* xp = X + (size_t)(row0 + r) * DIMC + k0;
          acc[r] += xp[0] * wv0 + xp[1] * wv1 + xp[2] * wv2 + xp[3] * wv3;
        }
      }
    }
  }
#pragma unroll
  for (int r = 0; r < GR; ++r) {
    if (row0 + r < N_NODESC) Y[(size_t)(row0 + r) * DIMC + t] = acc[r] * inv[row0 + r];
  }
}

// ---------------- aggregation: out = (sum_{src} Hs[src] + Hs[i]) * inv[i] + b ----------------
__global__ __launch_bounds__(128) void agg_kernel(const float* __restrict__ Hs, const float* __restrict__ inv,
                                                  const int* __restrict__ rowptr, const int* __restrict__ csr,
                                                  const float* __restrict__ bias, float* __restrict__ out,
                                                  int do_relu) {
  int i = blockIdx.x;
  int t = threadIdx.x;
  int beg = rowptr[i], end = rowptr[i + 1];
  float acc = Hs[(size_t)i * DIMC + t];
  int e = beg;
  for (; e + 4 <= end; e += 4) {
    int s0 = csr[e], s1 = csr[e + 1], s2 = csr[e + 2], s3 = csr[e + 3];
    float v0 = Hs[(size_t)s0 * DIMC + t];
    float v1 = Hs[(size_t)s1 * DIMC + t];
    float v2 = Hs[(size_t)s2 * DIMC + t];
    float v3 = Hs[(size_t)s3 * DIMC + t];
    acc += v0 + v1 + v2 + v3;
  }
  for (; e < end; ++e) acc += Hs[(size_t)csr[e] * DIMC + t];
  float o = acc * inv[i] + bias[t];
  if (do_relu) o = (o > 0.f) ? o : SLOPEF * o;
  out[(size_t)i * DIMC + t] = o;
}

// ---------------- pooling ----------------
__global__ __launch_bounds__(128) void pool_kernel(const float* __restrict__ G, const int* __restrict__ batch,
                                                   float* __restrict__ psum, int* __restrict__ pcnt) {
  int t = threadIdx.x;
  int n0 = blockIdx.x * 64;
  int nend = min(n0 + 64, N_NODESC);
  int cur = batch[n0];
  float acc = 0.f;
  int c = 0;
  for (int n = n0; n < nend; ++n) {
    int b = batch[n];
    if (b != cur) {
      atomicAdd(&psum[cur * DIMC + t], acc);
      if (t == 0) atomicAdd(&pcnt[cur], c);
      acc = 0.f;
      c = 0;
      cur = b;
    }
    acc += G[(size_t)n * DIMC + t];
    c += 1;
  }
  atomicAdd(&psum[cur * DIMC + t], acc);
  if (t == 0) atomicAdd(&pcnt[cur], c);
}

__global__ __launch_bounds__(128) void mean_kernel(const float* __restrict__ psA, const int* __restrict__ pcA,
                                                   const float* __restrict__ psB, const int* __restrict__ pcB,
                                                   float* __restrict__ hA, float* __restrict__ hB) {
  int dir = blockIdx.x >> 6, g = blockIdx.x & 63, t = threadIdx.x;
  const float* ps = dir ? psB : psA;
  const int* pc = dir ? pcB : pcA;
  float* h = dir ? hB : hA;
  h[g * DIMC + t] = ps[g * DIMC + t] / (float)max(pc[g], 1);
}

// ---------------- attention (64 tokens per side) ----------------
__global__ __launch_bounds__(128) void qkv_kernel(const float* __restrict__ hA, const float* __restrict__ hB,
                                                  const float* __restrict__ Wq, const float* __restrict__ bq,
                                                  const float* __restrict__ Wk, const float* __restrict__ bk,
                                                  const float* __restrict__ Wv, const float* __restrict__ bv,
                                                  float* __restrict__ Q0, float* __restrict__ K0, float* __restrict__ V0,
                                                  float* __restrict__ Q1, float* __restrict__ K1, float* __restrict__ V1) {
  __shared__ float xs[DIMC];
  int task = blockIdx.x >> 6, r = blockIdx.x & 63, t = threadIdx.x;
  const float *X, *W, *b;
  float* Y;
  switch (task) {
    case 0: X = hA; W = Wq; b = bq; Y = Q0; break;
    case 1: X = hB; W = Wk; b = bk; Y = K0; break;
    case 2: X = hB; W = Wv; b = bv; Y = V0; break;
    case 3: X = hB; W = Wq; b = bq; Y = Q1; break;
    case 4: X = hA; W = Wk; b = bk; Y = K1; break;
    default: X = hA; W = Wv; b = bv; Y = V1; break;
  }
  xs[t] = X[r * DIMC + t];
  __syncthreads();
  float acc = b[t];
  for (int k = 0; k < DIMC; ++k) acc += xs[k] * W[k * DIMC + t];
  Y[r * DIMC + t] = acc;
}

__global__ __launch_bounds__(64) void attn_kernel(const float* __restrict__ Q0, const float* __restrict__ K0,
                                                  const float* __restrict__ V0, const float* __restrict__ Q1,
                                                  const float* __restrict__ K1, const float* __restrict__ V1,
                                                  float* __restrict__ O0, float* __restrict__ O1) {
  __shared__ float ps[64];
  int b = blockIdx.x;
  int dir = b >> 8, h = (b >> 6) & 3, q = b & 63;
  const float* Q = dir ? Q1 : Q0;
  const float* K = dir ? K1 : K0;
  const float* V = dir ? V1 : V0;
  float* O = dir ? O1 : O0;
  int k = threadIdx.x;
  const float* qp = Q + q * DIMC + h * HDC;
  const float* kp = K + k * DIMC + h * HDC;
  float s = 0.f;
#pragma unroll
  for (int d = 0; d < HDC; ++d) s += qp[d] * kp[d];
  s *= SCALEF;
  float m = s;
#pragma unroll
  for (int off = 32; off >= 1; off >>= 1) m = fmaxf(m, __shfl_xor(m, off, 64));
  float p = __expf(s - m);
  float sum = p;
#pragma unroll
  for (int off = 32; off >= 1; off >>= 1) sum += __shfl_xor(sum, off, 64);
  p /= sum;
  ps[k] = p;
  __syncthreads();
  int half = k >> 5, d = k & 31;
  float acc = 0.f;
#pragma unroll
  for (int j = 0; j < 32; ++j) {
    int kk = half * 32 + j;
    acc += ps[kk] * V[kk * DIMC + h * HDC + d];
  }
  acc += __shfl_xor(acc, 32, 64);
  if (half == 0) O[q * DIMC + h * HDC + d] = acc;
}

__device__ inline float blk_sum128(float v, float* red) {
#pragma unroll
  for (int off = 32; off >= 1; off >>= 1) v += __shfl_xor(v, off, 64);
  if ((threadIdx.x & 63) == 0) red[threadIdx.x >> 6] = v;
  __syncthreads();
  float r = red[0] + red[1];
  __syncthreads();
  return r;
}

__global__ __launch_bounds__(128) void oln_kernel(const float* __restrict__ O0, const float* __restrict__ O1,
                                                  const float* __restrict__ hA, const float* __restrict__ hB,
                                                  const float* __restrict__ Wo, const float* __restrict__ bo,
                                                  const float* __restrict__ g1, const float* __restrict__ be1,
                                                  float* __restrict__ X0, float* __restrict__ X1) {
  __shared__ float os[DIMC];
  __shared__ float red[2];
  int dir = blockIdx.x >> 6, q = blockIdx.x & 63, t = threadIdx.x;
  const float* O = dir ? O1 : O0;
  const float* xq = dir ? hB : hA;
  float* Xo = dir ? X1 : X0;
  os[t] = O[q * DIMC + t];
  __syncthreads();
  float acc = bo[t] + xq[q * DIMC + t];
  for (int k = 0; k < DIMC; ++k) acc += os[k] * Wo[k * DIMC + t];
  float mean = blk_sum128(acc, red) * (1.f / DIMC);
  float d = acc - mean;
  float var = blk_sum128(d * d, red) * (1.f / DIMC);
  Xo[q * DIMC + t] = d * rsqrtf(var + EPSF) * g1[t] + be1[t];
}

__global__ __launch_bounds__(256) void ff1_kernel(const float* __restrict__ X0, const float* __restrict__ X1,
                                                  const float* __restrict__ Wf1, const float* __restrict__ bf1,
                                                  float* __restrict__ F0, float* __restrict__ F1) {
  __shared__ float xs[DIMC];
  int dir = blockIdx.x >> 6, q = blockIdx.x & 63, t = threadIdx.x;
  const float* X = dir ? X1 : X0;
  float* F = dir ? F1 : F0;
  if (t < DIMC) xs[t] = X[q * DIMC + t];
  __syncthreads();
  float acc = bf1[t];
  for (int k = 0; k < DIMC; ++k) acc += xs[k] * Wf1[k * 256 + t];
  acc = (acc > 0.f) ? acc : SLOPEF * acc;
  F[q * 256 + t] = acc;
}

__global__ __launch_bounds__(128) void ffln_kernel(const float* __restrict__ F0, const float* __restrict__ F1,
                                                   const float* __restrict__ X0, const float* __restrict__ X1,
                                                   const float* __restrict__ Wf2, const float* __restrict__ bf2,
                                                   const float* __restrict__ g2, const float* __restrict__ be2,
                                                   float* __restrict__ Y0, float* __restrict__ Y1) {
  __shared__ float fs[256];
  __shared__ float red[2];
  int dir = blockIdx.x >> 6, q = blockIdx.x & 63, t = threadIdx.x;
  const float* F = dir ? F1 : F0;
  const float* X = dir ? X1 : X0;
  float* Y = dir ? Y1 : Y0;
  fs[t] = F[q * 256 + t];
  fs[t + 128] = F[q * 256 + t + 128];
  __syncthreads();
  float acc = bf2[t] + X[q * DIMC + t];
  for (int k = 0; k < 256; ++k) acc += fs[k] * Wf2[k * DIMC + t];
  float mean = blk_sum128(acc, red) * (1.f / DIMC);
  float d = acc - mean;
  float var = blk_sum128(d * d, red) * (1.f / DIMC);
  Y[q * DIMC + t] = d * rsqrtf(var + EPSF) * g2[t] + be2[t];
}

__global__ __launch_bounds__(128) void head_kernel(const float* __restrict__ Y0, const float* __restrict__ Y1,
                                                   const float* __restrict__ Wl1, const float* __restrict__ bl1,
                                                   const float* __restrict__ Wl2, const float* __restrict__ bl2,
                                                   float* __restrict__ out) {
  __shared__ float cs[256];
  __shared__ float red[2];
  int g = blockIdx.x, t = threadIdx.x;
  cs[t] = Y0[g * DIMC + t];
  cs[t + 128] = Y1[g * DIMC + t];
  __syncthreads();
  float acc = bl1[t];
  for (int k = 0; k < 256; ++k) acc += cs[k] * Wl1[k * DIMC + t];
  acc = fmaxf(acc, 0.f);
  float s = blk_sum128(acc * Wl2[t], red);
  if (t == 0) out[g] = s + bl2[0];
}

// ---------------- host ----------------
extern "C" void kernel_launch(void* const* d_in, const int* in_sizes, int n_in,
                              void* d_out, int out_size, void* d_ws, size_t ws_size,
                              hipStream_t stream) {
  const float* xA = (const float*)d_in[0];
  const float* xB = (const float*)d_in[1];
  const int* eiA = (const int*)d_in[2];
  const int* eiB = (const int*)d_in[3];
  const int* batA = (const int*)d_in[4];
  const int* batB = (const int*)d_in[5];
  const float* WA1 = (const float*)d_in[6];
  const float* WA2 = (const float*)d_in[7];
  const float* WB1 = (const float*)d_in[8];
  const float* WB2 = (const float*)d_in[9];
  const float* Wq = (const float*)d_in[10];
  const float* Wk = (const float*)d_in[11];
  const float* Wv = (const float*)d_in[12];
  const float* Wo = (const float*)d_in[13];
  const float* Wf1 = (const float*)d_in[14];
  const float* Wf2 = (const float*)d_in[15];
  const float* Wl1 = (const float*)d_in[16];
  const float* Wl2 = (const float*)d_in[17];
  const float* bA1 = (const float*)d_in[18];
  const float* bA2 = (const float*)d_in[19];
  const float* bB1 = (const float*)d_in[20];
  const float* bB2 = (const float*)d_in[21];
  const float* bq = (const float*)d_in[22];
  const float* bk = (const float*)d_in[23];
  const float* bv = (const float*)d_in[24];
  const float* bo = (const float*)d_in[25];
  const float* bf1 = (const float*)d_in[26];
  const float* bf2 = (const float*)d_in[27];
  const float* bl1 = (const float*)d_in[28];
  const float* bl2 = (const float*)d_in[29];
  const float* g1 = (const float*)d_in[30];
  const float* be1 = (const float*)d_in[31];
  const float* g2 = (const float*)d_in[32];
  const float* be2 = (const float*)d_in[33];

  char* base = (char*)d_ws;
  size_t off = 0;
  auto alloc = [&](size_t bytes) -> char* {
    char* r = base + off;
    off += (bytes + 255) & ~(size_t)255;
    return r;
  };
  float* h_buf = (float*)alloc((size_t)N_NODESC * DIMC * 4);
  float* g_buf = (float*)alloc((size_t)N_NODESC * DIMC * 4);
  int* csr = (int*)alloc((size_t)N_EDGESC * 4);
  int* rowptr = (int*)alloc((size_t)(N_NODESC + 1) * 4);
  float* inv = (float*)alloc((size_t)N_NODESC * 4);
  size_t zoff0 = off;
  int* cnt = (int*)alloc((size_t)N_NODESC * 4);
  int* fillc = (int*)alloc((size_t)N_NODESC * 4);
  size_t zbytes = off - zoff0;  // cnt+fill region (zeroed per side)
  size_t poff0 = off;
  float* psA = (float*)alloc(NGC * DIMC * 4);
  float* psB = (float*)alloc(NGC * DIMC * 4);
  int* pcA = (int*)alloc(NGC * 4);
  int* pcB = (int*)alloc(NGC * 4);
  size_t pbytes = off - poff0;  // pool region (zeroed once per call)
  float* mhA = (float*)alloc(NGC * DIMC * 4);
  float* mhB = (float*)alloc(NGC * DIMC * 4);
  float* Q0 = (float*)alloc(NGC * DIMC * 4);
  float* K0 = (float*)alloc(NGC * DIMC * 4);
  float* V0 = (float*)alloc(NGC * DIMC * 4);
  float* Q1 = (float*)alloc(NGC * DIMC * 4);
  float* K1 = (float*)alloc(NGC * DIMC * 4);
  float* V1 = (float*)alloc(NGC * DIMC * 4);
  float* O0 = (float*)alloc(NGC * DIMC * 4);
  float* O1 = (float*)alloc(NGC * DIMC * 4);
  float* X0 = (float*)alloc(NGC * DIMC * 4);
  float* X1 = (float*)alloc(NGC * DIMC * 4);
  float* F0 = (float*)alloc(NGC * 256 * 4);
  float* F1 = (float*)alloc(NGC * 256 * 4);
  float* Y0 = (float*)alloc(NGC * DIMC * 4);
  float* Y1 = (float*)alloc(NGC * DIMC * 4);

  hipMemsetAsync(base + poff0, 0, pbytes, stream);

  const int egrid = N_EDGESC / 256;          // 3125
  const int ggrid = (N_NODESC + GR - 1) / GR;  // 782
  const int pgrid = (N_NODESC + 63) / 64;      // 782

  for (int side = 0; side < 2; ++side) {
    const float* x = side ? xB : xA;
    const int* ei = side ? eiB : eiA;
    const int* bat = side ? batB : batA;
    const float* W1 = side ? WB1 : WA1;
    const float* b1 = side ? bB1 : bA1;
    const float* W2 = side ? WB2 : WA2;
    const float* b2 = side ? bB2 : bA2;
    float* ps = side ? psB : psA;
    int* pc = side ? pcB : pcA;

    hipMemsetAsync(base + zoff0, 0, zbytes, stream);
    count_kernel<<<egrid, 256, 0, stream>>>(ei, cnt);
    scan_kernel<<<1, 1024, 0, stream>>>(cnt, rowptr, inv);
    fill_kernel<<<egrid, 256, 0, stream>>>(ei, rowptr, fillc, csr);
    gemm_enc<<<ggrid, 128, 0, stream>>>(x, W1, inv, h_buf);
    agg_kernel<<<N_NODESC, 128, 0, stream>>>(h_buf, inv, rowptr, csr, b1, g_buf, 1);
    gemm_enc<<<ggrid, 128, 0, stream>>>(g_buf, W2, inv, h_buf);
    agg_kernel<<<N_NODESC, 128, 0, stream>>>(h_buf, inv, rowptr, csr, b2, g_buf, 0);
    pool_kernel<<<pgrid, 128, 0, stream>>>(g_buf, bat, ps, pc);
  }

  mean_kernel<<<128, 128, 0, stream>>>(psA, pcA, psB, pcB, mhA, mhB);
  qkv_kernel<<<384, 128, 0, stream>>>(mhA, mhB, Wq, bq, Wk, bk, Wv, bv, Q0, K0, V0, Q1, K1, V1);
  attn_kernel<<<512, 64, 0, stream>>>(Q0, K0, V0, Q1, K1, V1, O0, O1);
  oln_kernel<<<128, 128, 0, stream>>>(O0, O1, mhA, mhB, Wo, bo, g1, be1, X0, X1);
  ff1_kernel<<<128, 256, 0, stream>>>(X0, X1, Wf1, bf1, F0, F1);
  ffln_kernel<<<128, 128, 0, stream>>>(F0, F1, X0, X1, Wf2, bf2, g2, be2, Y0, Y1);
  head_kernel<<<64, 128, 0, stream>>>(Y0, Y1, Wl1, bl1, Wl2, bl2, (float*)d_out);
}

// Round 2
// 872.374 us; speedup vs baseline: 2.4133x; 2.4133x over previous
//
#include <hip/hip_runtime.h>

#define N_NODESC 50000
#define N_EDGESC 800000
#define DIMC 128
#define NGC 64
#define HDC 32
#define SLOPEF 0.01f
#define EPSF 1e-5f
#define SCALEF 0.17677669529663687f  // 32^-0.5

// ---------------- CSR build ----------------
__global__ __launch_bounds__(256) void count_kernel(const int* __restrict__ ei, int* __restrict__ cnt) {
  int e = blockIdx.x * 256 + threadIdx.x;
  if (e < N_EDGESC) atomicAdd(&cnt[ei[N_EDGESC + e]], 1);
}

__global__ __launch_bounds__(1024) void scan_kernel(const int* __restrict__ cnt, int* __restrict__ rowptr,
                                                    float* __restrict__ inv) {
  __shared__ int sd[1024];
  const int n = N_NODESC;
  const int per = (n + 1023) / 1024;  // 49
  int t = threadIdx.x;
  int lo = t * per, hi = min(lo + per, n);
  int s = 0;
  for (int i = lo; i < hi; ++i) {
    int v = cnt[i];
    inv[i] = rsqrtf((float)v + 1.0f);
    s += v;
  }
  sd[t] = s;
  __syncthreads();
  for (int off = 1; off < 1024; off <<= 1) {
    int tv = (t >= off) ? sd[t - off] : 0;
    __syncthreads();
    sd[t] += tv;
    __syncthreads();
  }
  int run = sd[t] - s;  // exclusive prefix for this thread's range
  for (int i = lo; i < hi; ++i) {
    rowptr[i] = run;
    run += cnt[i];
  }
  if (t == 1023) rowptr[n] = sd[1023];
}

__global__ __launch_bounds__(256) void fill_kernel(const int* __restrict__ ei, const int* __restrict__ rowptr,
                                                   int* __restrict__ fillc, int* __restrict__ csr) {
  int e = blockIdx.x * 256 + threadIdx.x;
  if (e < N_EDGESC) {
    int s = ei[e];
    int d = ei[N_EDGESC + e];
    int pos = rowptr[d] + atomicAdd(&fillc[d], 1);
    csr[pos] = s;
  }
}

// ---------------- encoder GEMM: Y = (X @ W) * inv[row] ----------------
// 256 thr, BM=32 rows, W(64KB)+Xtile(16KB) LDS = 80KB -> 2 blocks/CU, 2 waves/SIMD.
// Per-thread 4 rows x 4 cols register tile; all LDS via ds_read_b128.
#define BMR 32
__global__ __launch_bounds__(256, 2) void gemm_enc(const float* __restrict__ X, const float* __restrict__ W,
                                                   const float* __restrict__ inv, float* __restrict__ Y) {
  __shared__ float Ws[DIMC * DIMC];   // 64 KB
  __shared__ float Xs[BMR * DIMC];    // 16 KB
  int t = threadIdx.x;
  int row0 = blockIdx.x * BMR;
#pragma unroll
  for (int i = 0; i < DIMC * DIMC; i += 1024) {
    *(float4*)&Ws[i + t * 4] = *(const float4*)&W[i + t * 4];
  }
  {
    const size_t lim = (size_t)N_NODESC * DIMC;
#pragma unroll
    for (int i = 0; i < BMR * DIMC; i += 1024) {
      int li = i + t * 4;
      size_t gi = (size_t)row0 * DIMC + li;
      float4 v = make_float4(0.f, 0.f, 0.f, 0.f);
      if (gi < lim) v = *(const float4*)&X[gi];
      *(float4*)&Xs[li] = v;
    }
  }
  __syncthreads();
  const int cg = (t & 31) * 4;   // col base (float4)
  const int rg = (t >> 5) * 4;   // row base (4 rows)
  float acc[4][4];
#pragma unroll
  for (int i = 0; i < 4; ++i)
#pragma unroll
    for (int j = 0; j < 4; ++j) acc[i][j] = 0.f;
  for (int k0 = 0; k0 < DIMC; k0 += 4) {
    float4 xv[4], wv[4];
#pragma unroll
    for (int i = 0; i < 4; ++i) xv[i] = *(const float4*)&Xs[(rg + i) * DIMC + k0];
#pragma unroll
    for (int kk = 0; kk < 4; ++kk) wv[kk] = *(const float4*)&Ws[(k0 + kk) * DIMC + cg];
#pragma unroll
    for (int i = 0; i < 4; ++i) {
      const float* xp = (const float*)&xv[i];
#pragma unroll
      for (int kk = 0; kk < 4; ++kk) {
        float xs = xp[kk];
        acc[i][0] += xs * wv[kk].x;
        acc[i][1] += xs * wv[kk].y;
        acc[i][2] += xs * wv[kk].z;
        acc[i][3] += xs * wv[kk].w;
      }
    }
  }
#pragma unroll
  for (int i = 0; i < 4; ++i) {
    int r = row0 + rg + i;
    if (r < N_NODESC) {
      float s = inv[r];
      float4 o = make_float4(acc[i][0] * s, acc[i][1] * s, acc[i][2] * s, acc[i][3] * s);
      *(float4*)&Y[(size_t)r * DIMC + cg] = o;
    }
  }
}

// ---------------- aggregation: out = (sum_{src} Hs[src] + Hs[i]) * inv[i] + b ----------------
// One wave per node; lane = (colgroup, edge-slot); float4 gathers (512B/edge exact).
__global__ __launch_bounds__(256) void agg_kernel(const float* __restrict__ Hs, const float* __restrict__ inv,
                                                  const int* __restrict__ rowptr, const int* __restrict__ csr,
                                                  const float* __restrict__ bias, float* __restrict__ out,
                                                  int do_relu) {
  int node = blockIdx.x * 4 + (threadIdx.x >> 6);
  if (node >= N_NODESC) return;
  int lane = threadIdx.x & 63;
  int cg = (lane & 31) * 4;
  int slot = lane >> 5;
  int beg = rowptr[node], end = rowptr[node + 1];
  float4 acc = make_float4(0.f, 0.f, 0.f, 0.f);
  for (int e = beg + slot; e < end; e += 2) {
    int s = csr[e];
    float4 v = *(const float4*)&Hs[(size_t)s * DIMC + cg];
    acc.x += v.x; acc.y += v.y; acc.z += v.z; acc.w += v.w;
  }
  acc.x += __shfl_xor(acc.x, 32, 64);
  acc.y += __shfl_xor(acc.y, 32, 64);
  acc.z += __shfl_xor(acc.z, 32, 64);
  acc.w += __shfl_xor(acc.w, 32, 64);
  if (slot == 0) {
    float4 self = *(const float4*)&Hs[(size_t)node * DIMC + cg];
    float sc = inv[node];
    float4 b = *(const float4*)&bias[cg];
    float4 o;
    o.x = (acc.x + self.x) * sc + b.x;
    o.y = (acc.y + self.y) * sc + b.y;
    o.z = (acc.z + self.z) * sc + b.z;
    o.w = (acc.w + self.w) * sc + b.w;
    if (do_relu) {
      o.x = (o.x > 0.f) ? o.x : SLOPEF * o.x;
      o.y = (o.y > 0.f) ? o.y : SLOPEF * o.y;
      o.z = (o.z > 0.f) ? o.z : SLOPEF * o.z;
      o.w = (o.w > 0.f) ? o.w : SLOPEF * o.w;
    }
    *(float4*)&out[(size_t)node * DIMC + cg] = o;
  }
}

// ---------------- pooling ----------------
__global__ __launch_bounds__(128) void pool_kernel(const float* __restrict__ G, const int* __restrict__ batch,
                                                   float* __restrict__ psum, int* __restrict__ pcnt) {
  int t = threadIdx.x;
  int n0 = blockIdx.x * 64;
  int nend = min(n0 + 64, N_NODESC);
  int cur = batch[n0];
  float acc = 0.f;
  int c = 0;
  for (int n = n0; n < nend; ++n) {
    int b = batch[n];
    if (b != cur) {
      atomicAdd(&psum[cur * DIMC + t], acc);
      if (t == 0) atomicAdd(&pcnt[cur], c);
      acc = 0.f;
      c = 0;
      cur = b;
    }
    acc += G[(size_t)n * DIMC + t];
    c += 1;
  }
  atomicAdd(&psum[cur * DIMC + t], acc);
  if (t == 0) atomicAdd(&pcnt[cur], c);
}

__global__ __launch_bounds__(128) void mean_kernel(const float* __restrict__ psA, const int* __restrict__ pcA,
                                                   const float* __restrict__ psB, const int* __restrict__ pcB,
                                                   float* __restrict__ hA, float* __restrict__ hB) {
  int dir = blockIdx.x >> 6, g = blockIdx.x & 63, t = threadIdx.x;
  const float* ps = dir ? psB : psA;
  const int* pc = dir ? pcB : pcA;
  float* h = dir ? hB : hA;
  h[g * DIMC + t] = ps[g * DIMC + t] / (float)max(pc[g], 1);
}

// ---------------- attention (64 tokens per side) ----------------
__global__ __launch_bounds__(128) void qkv_kernel(const float* __restrict__ hA, const float* __restrict__ hB,
                                                  const float* __restrict__ Wq, const float* __restrict__ bq,
                                                  const float* __restrict__ Wk, const float* __restrict__ bk,
                                                  const float* __restrict__ Wv, const float* __restrict__ bv,
                                                  float* __restrict__ Q0, float* __restrict__ K0, float* __restrict__ V0,
                                                  float* __restrict__ Q1, float* __restrict__ K1, float* __restrict__ V1) {
  __shared__ float xs[DIMC];
  int task = blockIdx.x >> 6, r = blockIdx.x & 63, t = threadIdx.x;
  const float *X, *W, *b;
  float* Y;
  switch (task) {
    case 0: X = hA; W = Wq; b = bq; Y = Q0; break;
    case 1: X = hB; W = Wk; b = bk; Y = K0; break;
    case 2: X = hB; W = Wv; b = bv; Y = V0; break;
    case 3: X = hB; W = Wq; b = bq; Y = Q1; break;
    case 4: X = hA; W = Wk; b = bk; Y = K1; break;
    default: X = hA; W = Wv; b = bv; Y = V1; break;
  }
  xs[t] = X[r * DIMC + t];
  __syncthreads();
  float acc = b[t];
  for (int k = 0; k < DIMC; ++k) acc += xs[k] * W[k * DIMC + t];
  Y[r * DIMC + t] = acc;
}

__global__ __launch_bounds__(64) void attn_kernel(const float* __restrict__ Q0, const float* __restrict__ K0,
                                                  const float* __restrict__ V0, const float* __restrict__ Q1,
                                                  const float* __restrict__ K1, const float* __restrict__ V1,
                                                  float* __restrict__ O0, float* __restrict__ O1) {
  __shared__ float ps[64];
  int b = blockIdx.x;
  int dir = b >> 8, h = (b >> 6) & 3, q = b & 63;
  const float* Q = dir ? Q1 : Q0;
  const float* K = dir ? K1 : K0;
  const float* V = dir ? V1 : V0;
  float* O = dir ? O1 : O0;
  int k = threadIdx.x;
  const float* qp = Q + q * DIMC + h * HDC;
  const float* kp = K + k * DIMC + h * HDC;
  float s = 0.f;
#pragma unroll
  for (int d = 0; d < HDC; ++d) s += qp[d] * kp[d];
  s *= SCALEF;
  float m = s;
#pragma unroll
  for (int off = 32; off >= 1; off >>= 1) m = fmaxf(m, __shfl_xor(m, off, 64));
  float p = __expf(s - m);
  float sum = p;
#pragma unroll
  for (int off = 32; off >= 1; off >>= 1) sum += __shfl_xor(sum, off, 64);
  p /= sum;
  ps[k] = p;
  __syncthreads();
  int half = k >> 5, d = k & 31;
  float acc = 0.f;
#pragma unroll
  for (int j = 0; j < 32; ++j) {
    int kk = half * 32 + j;
    acc += ps[kk] * V[kk * DIMC + h * HDC + d];
  }
  acc += __shfl_xor(acc, 32, 64);
  if (half == 0) O[q * DIMC + h * HDC + d] = acc;
}

__device__ inline float blk_sum128(float v, float* red) {
#pragma unroll
  for (int off = 32; off >= 1; off >>= 1) v += __shfl_xor(v, off, 64);
  if ((threadIdx.x & 63) == 0) red[threadIdx.x >> 6] = v;
  __syncthreads();
  float r = red[0] + red[1];
  __syncthreads();
  return r;
}

__global__ __launch_bounds__(128) void oln_kernel(const float* __restrict__ O0, const float* __restrict__ O1,
                                                  const float* __restrict__ hA, const float* __restrict__ hB,
                                                  const float* __restrict__ Wo, const float* __restrict__ bo,
                                                  const float* __restrict__ g1, const float* __restrict__ be1,
                                                  float* __restrict__ X0, float* __restrict__ X1) {
  __shared__ float os[DIMC];
  __shared__ float red[2];
  int dir = blockIdx.x >> 6, q = blockIdx.x & 63, t = threadIdx.x;
  const float* O = dir ? O1 : O0;
  const float* xq = dir ? hB : hA;
  float* Xo = dir ? X1 : X0;
  os[t] = O[q * DIMC + t];
  __syncthreads();
  float acc = bo[t] + xq[q * DIMC + t];
  for (int k = 0; k < DIMC; ++k) acc += os[k] * Wo[k * DIMC + t];
  float mean = blk_sum128(acc, red) * (1.f / DIMC);
  float d = acc - mean;
  float var = blk_sum128(d * d, red) * (1.f / DIMC);
  Xo[q * DIMC + t] = d * rsqrtf(var + EPSF) * g1[t] + be1[t];
}

__global__ __launch_bounds__(256) void ff1_kernel(const float* __restrict__ X0, const float* __restrict__ X1,
                                                  const float* __restrict__ Wf1, const float* __restrict__ bf1,
                                                  float* __restrict__ F0, float* __restrict__ F1) {
  __shared__ float xs[DIMC];
  int dir = blockIdx.x >> 6, q = blockIdx.x & 63, t = threadIdx.x;
  const float* X = dir ? X1 : X0;
  float* F = dir ? F1 : F0;
  if (t < DIMC) xs[t] = X[q * DIMC + t];
  __syncthreads();
  float acc = bf1[t];
  for (int k = 0; k < DIMC; ++k) acc += xs[k] * Wf1[k * 256 + t];
  acc = (acc > 0.f) ? acc : SLOPEF * acc;
  F[q * 256 + t] = acc;
}

__global__ __launch_bounds__(128) void ffln_kernel(const float* __restrict__ F0, const float* __restrict__ F1,
                                                   const float* __restrict__ X0, const float* __restrict__ X1,
                                                   const float* __restrict__ Wf2, const float* __restrict__ bf2,
                                                   const float* __restrict__ g2, const float* __restrict__ be2,
                                                   float* __restrict__ Y0, float* __restrict__ Y1) {
  __shared__ float fs[256];
  __shared__ float red[2];
  int dir = blockIdx.x >> 6, q = blockIdx.x & 63, t = threadIdx.x;
  const float* F = dir ? F1 : F0;
  const float* X = dir ? X1 : X0;
  float* Y = dir ? Y1 : Y0;
  fs[t] = F[q * 256 + t];
  fs[t + 128] = F[q * 256 + t + 128];
  __syncthreads();
  float acc = bf2[t] + X[q * DIMC + t];
  for (int k = 0; k < 256; ++k) acc += fs[k] * Wf2[k * DIMC + t];
  float mean = blk_sum128(acc, red) * (1.f / DIMC);
  float d = acc - mean;
  float var = blk_sum128(d * d, red) * (1.f / DIMC);
  Y[q * DIMC + t] = d * rsqrtf(var + EPSF) * g2[t] + be2[t];
}

__global__ __launch_bounds__(128) void head_kernel(const float* __restrict__ Y0, const float* __restrict__ Y1,
                                                   const float* __restrict__ Wl1, const float* __restrict__ bl1,
                                                   const float* __restrict__ Wl2, const float* __restrict__ bl2,
                                                   float* __restrict__ out) {
  __shared__ float cs[256];
  __shared__ float red[2];
  int g = blockIdx.x, t = threadIdx.x;
  cs[t] = Y0[g * DIMC + t];
  cs[t + 128] = Y1[g * DIMC + t];
  __syncthreads();
  float acc = bl1[t];
  for (int k = 0; k < 256; ++k) acc += cs[k] * Wl1[k * DIMC + t];
  acc = fmaxf(acc, 0.f);
  float s = blk_sum128(acc * Wl2[t], red);
  if (t == 0) out[g] = s + bl2[0];
}

// ---------------- host ----------------
extern "C" void kernel_launch(void* const* d_in, const int* in_sizes, int n_in,
                              void* d_out, int out_size, void* d_ws, size_t ws_size,
                              hipStream_t stream) {
  const float* xA = (const float*)d_in[0];
  const float* xB = (const float*)d_in[1];
  const int* eiA = (const int*)d_in[2];
  const int* eiB = (const int*)d_in[3];
  const int* batA = (const int*)d_in[4];
  const int* batB = (const int*)d_in[5];
  const float* WA1 = (const float*)d_in[6];
  const float* WA2 = (const float*)d_in[7];
  const float* WB1 = (const float*)d_in[8];
  const float* WB2 = (const float*)d_in[9];
  const float* Wq = (const float*)d_in[10];
  const float* Wk = (const float*)d_in[11];
  const float* Wv = (const float*)d_in[12];
  const float* Wo = (const float*)d_in[13];
  const float* Wf1 = (const float*)d_in[14];
  const float* Wf2 = (const float*)d_in[15];
  const float* Wl1 = (const float*)d_in[16];
  const float* Wl2 = (const float*)d_in[17];
  const float* bA1 = (const float*)d_in[18];
  const float* bA2 = (const float*)d_in[19];
  const float* bB1 = (const float*)d_in[20];
  const float* bB2 = (const float*)d_in[21];
  const float* bq = (const float*)d_in[22];
  const float* bk = (const float*)d_in[23];
  const float* bv = (const float*)d_in[24];
  const float* bo = (const float*)d_in[25];
  const float* bf1 = (const float*)d_in[26];
  const float* bf2 = (const float*)d_in[27];
  const float* bl1 = (const float*)d_in[28];
  const float* bl2 = (const float*)d_in[29];
  const float* g1 = (const float*)d_in[30];
  const float* be1 = (const float*)d_in[31];
  const float* g2 = (const float*)d_in[32];
  const float* be2 = (const float*)d_in[33];

  char* base = (char*)d_ws;
  size_t off = 0;
  auto alloc = [&](size_t bytes) -> char* {
    char* r = base + off;
    off += (bytes + 255) & ~(size_t)255;
    return r;
  };
  float* h_buf = (float*)alloc((size_t)N_NODESC * DIMC * 4);
  float* g_buf = (float*)alloc((size_t)N_NODESC * DIMC * 4);
  int* csr = (int*)alloc((size_t)N_EDGESC * 4);
  int* rowptr = (int*)alloc((size_t)(N_NODESC + 1) * 4);
  float* inv = (float*)alloc((size_t)N_NODESC * 4);
  size_t zoff0 = off;
  int* cnt = (int*)alloc((size_t)N_NODESC * 4);
  int* fillc = (int*)alloc((size_t)N_NODESC * 4);
  size_t zbytes = off - zoff0;  // cnt+fill region (zeroed per side)
  size_t poff0 = off;
  float* psA = (float*)alloc(NGC * DIMC * 4);
  float* psB = (float*)alloc(NGC * DIMC * 4);
  int* pcA = (int*)alloc(NGC * 4);
  int* pcB = (int*)alloc(NGC * 4);
  size_t pbytes = off - poff0;  // pool region (zeroed once per call)
  float* mhA = (float*)alloc(NGC * DIMC * 4);
  float* mhB = (float*)alloc(NGC * DIMC * 4);
  float* Q0 = (float*)alloc(NGC * DIMC * 4);
  float* K0 = (float*)alloc(NGC * DIMC * 4);
  float* V0 = (float*)alloc(NGC * DIMC * 4);
  float* Q1 = (float*)alloc(NGC * DIMC * 4);
  float* K1 = (float*)alloc(NGC * DIMC * 4);
  float* V1 = (float*)alloc(NGC * DIMC * 4);
  float* O0 = (float*)alloc(NGC * DIMC * 4);
  float* O1 = (float*)alloc(NGC * DIMC * 4);
  float* X0 = (float*)alloc(NGC * DIMC * 4);
  float* X1 = (float*)alloc(NGC * DIMC * 4);
  float* F0 = (float*)alloc(NGC * 256 * 4);
  float* F1 = (float*)alloc(NGC * 256 * 4);
  float* Y0 = (float*)alloc(NGC * DIMC * 4);
  float* Y1 = (float*)alloc(NGC * DIMC * 4);

  hipMemsetAsync(base + poff0, 0, pbytes, stream);

  const int egrid = N_EDGESC / 256;            // 3125
  const int ggrid = (N_NODESC + BMR - 1) / BMR;  // 1563
  const int agrid = (N_NODESC + 3) / 4;          // 12500
  const int pgrid = (N_NODESC + 63) / 64;        // 782

  for (int side = 0; side < 2; ++side) {
    const float* x = side ? xB : xA;
    const int* ei = side ? eiB : eiA;
    const int* bat = side ? batB : batA;
    const float* W1 = side ? WB1 : WA1;
    const float* b1 = side ? bB1 : bA1;
    const float* W2 = side ? WB2 : WA2;
    const float* b2 = side ? bB2 : bA2;
    float* ps = side ? psB : psA;
    int* pc = side ? pcB : pcA;

    hipMemsetAsync(base + zoff0, 0, zbytes, stream);
    count_kernel<<<egrid, 256, 0, stream>>>(ei, cnt);
    scan_kernel<<<1, 1024, 0, stream>>>(cnt, rowptr, inv);
    fill_kernel<<<egrid, 256, 0, stream>>>(ei, rowptr, fillc, csr);
    gemm_enc<<<ggrid, 256, 0, stream>>>(x, W1, inv, h_buf);
    agg_kernel<<<agrid, 256, 0, stream>>>(h_buf, inv, rowptr, csr, b1, g_buf, 1);
    gemm_enc<<<ggrid, 256, 0, stream>>>(g_buf, W2, inv, h_buf);
    agg_kernel<<<agrid, 256, 0, stream>>>(h_buf, inv, rowptr, csr, b2, g_buf, 0);
    pool_kernel<<<pgrid, 128, 0, stream>>>(g_buf, bat, ps, pc);
  }

  mean_kernel<<<128, 128, 0, stream>>>(psA, pcA, psB, pcB, mhA, mhB);
  qkv_kernel<<<384, 128, 0, stream>>>(mhA, mhB, Wq, bq, Wk, bk, Wv, bv, Q0, K0, V0, Q1, K1, V1);
  attn_kernel<<<512, 64, 0, stream>>>(Q0, K0, V0, Q1, K1, V1, O0, O1);
  oln_kernel<<<128, 128, 0, stream>>>(O0, O1, mhA, mhB, Wo, bo, g1, be1, X0, X1);
  ff1_kernel<<<128, 256, 0, stream>>>(X0, X1, Wf1, bf1, F0, F1);
  ffln_kernel<<<128, 128, 0, stream>>>(F0, F1, X0, X1, Wf2, bf2, g2, be2, Y0, Y1);
  head_kernel<<<64, 128, 0, stream>>>(Y0, Y1, Wl1, bl1, Wl2, bl2, (float*)d_out);
}

// Round 3
// 640.090 us; speedup vs baseline: 3.2890x; 1.3629x over previous
//
#include <hip/hip_runtime.h>

#define N_NODESC 50000
#define N_EDGESC 800000
#define DIMC 128
#define NGC 64
#define HDC 32
#define SLOPEF 0.01f
#define EPSF 1e-5f
#define SCALEF 0.17677669529663687f  // 32^-0.5
#define SCAN_G ((N_NODESC + 255) / 256)  // 196

// ---------------- CSR build ----------------
__global__ __launch_bounds__(256) void count_kernel(const int* __restrict__ ei, int* __restrict__ cnt) {
  int e = blockIdx.x * 256 + threadIdx.x;
  if (e < N_EDGESC) atomicAdd(&cnt[ei[N_EDGESC + e]], 1);
}

// per-block sum of cnt + inv[] compute
__global__ __launch_bounds__(256) void degsum_kernel(const int* __restrict__ cnt, float* __restrict__ inv,
                                                     int* __restrict__ bsum) {
  int i = blockIdx.x * 256 + threadIdx.x;
  int v = 0;
  if (i < N_NODESC) {
    v = cnt[i];
    inv[i] = rsqrtf((float)v + 1.0f);
  }
  int w = v;
#pragma unroll
  for (int off = 32; off >= 1; off >>= 1) w += __shfl_xor(w, off, 64);
  __shared__ int sd[4];
  if ((threadIdx.x & 63) == 0) sd[threadIdx.x >> 6] = w;
  __syncthreads();
  if (threadIdx.x == 0) bsum[blockIdx.x] = sd[0] + sd[1] + sd[2] + sd[3];
}

// exclusive scan of the 196 block sums (single small block)
__global__ __launch_bounds__(256) void scanb_kernel(const int* __restrict__ bsum, int* __restrict__ bbase) {
  __shared__ int sd[256];
  int t = threadIdx.x;
  int v = (t < SCAN_G) ? bsum[t] : 0;
  sd[t] = v;
  __syncthreads();
  for (int off = 1; off < 256; off <<= 1) {
    int u = (t >= off) ? sd[t - off] : 0;
    __syncthreads();
    sd[t] += u;
    __syncthreads();
  }
  bbase[t] = sd[t] - v;  // exclusive prefix
}

// rowptr[i] = bbase[blk] + intra-block exclusive prefix of cnt
__global__ __launch_bounds__(256) void rowptr_kernel(const int* __restrict__ cnt, const int* __restrict__ bbase,
                                                     int* __restrict__ rowptr) {
  __shared__ int sd[256];
  int t = threadIdx.x;
  int i = blockIdx.x * 256 + t;
  int v = (i < N_NODESC) ? cnt[i] : 0;
  sd[t] = v;
  __syncthreads();
  for (int off = 1; off < 256; off <<= 1) {
    int u = (t >= off) ? sd[t - off] : 0;
    __syncthreads();
    sd[t] += u;
    __syncthreads();
  }
  if (i < N_NODESC) rowptr[i] = bbase[blockIdx.x] + sd[t] - v;
  if (i == N_NODESC - 1) rowptr[N_NODESC] = N_EDGESC;  // all dsts in range -> total is constant
}

__global__ __launch_bounds__(256) void fill_kernel(const int* __restrict__ ei, const int* __restrict__ rowptr,
                                                   int* __restrict__ fillc, int* __restrict__ csr) {
  int e = blockIdx.x * 256 + threadIdx.x;
  if (e < N_EDGESC) {
    int s = ei[e];
    int d = ei[N_EDGESC + e];
    int pos = rowptr[d] + atomicAdd(&fillc[d], 1);
    csr[pos] = s;
  }
}

// ---------------- encoder GEMM: Y = (X @ W) * inv[row] ----------------
// 256 thr, BM=32 rows, W(64KB)+Xtile(16KB) LDS = 80KB -> 2 blocks/CU, 2 waves/SIMD.
// Per-thread 4 rows x 4 cols register tile; all LDS via ds_read_b128.
#define BMR 32
__global__ __launch_bounds__(256, 2) void gemm_enc(const float* __restrict__ X, const float* __restrict__ W,
                                                   const float* __restrict__ inv, float* __restrict__ Y) {
  __shared__ float Ws[DIMC * DIMC];   // 64 KB
  __shared__ float Xs[BMR * DIMC];    // 16 KB
  int t = threadIdx.x;
  int row0 = blockIdx.x * BMR;
#pragma unroll
  for (int i = 0; i < DIMC * DIMC; i += 1024) {
    *(float4*)&Ws[i + t * 4] = *(const float4*)&W[i + t * 4];
  }
  {
    const size_t lim = (size_t)N_NODESC * DIMC;
#pragma unroll
    for (int i = 0; i < BMR * DIMC; i += 1024) {
      int li = i + t * 4;
      size_t gi = (size_t)row0 * DIMC + li;
      float4 v = make_float4(0.f, 0.f, 0.f, 0.f);
      if (gi < lim) v = *(const float4*)&X[gi];
      *(float4*)&Xs[li] = v;
    }
  }
  __syncthreads();
  const int cg = (t & 31) * 4;   // col base (float4)
  const int rg = (t >> 5) * 4;   // row base (4 rows)
  float acc[4][4];
#pragma unroll
  for (int i = 0; i < 4; ++i)
#pragma unroll
    for (int j = 0; j < 4; ++j) acc[i][j] = 0.f;
  for (int k0 = 0; k0 < DIMC; k0 += 4) {
    float4 xv[4], wv[4];
#pragma unroll
    for (int i = 0; i < 4; ++i) xv[i] = *(const float4*)&Xs[(rg + i) * DIMC + k0];
#pragma unroll
    for (int kk = 0; kk < 4; ++kk) wv[kk] = *(const float4*)&Ws[(k0 + kk) * DIMC + cg];
#pragma unroll
    for (int i = 0; i < 4; ++i) {
      const float* xp = (const float*)&xv[i];
#pragma unroll
      for (int kk = 0; kk < 4; ++kk) {
        float xs = xp[kk];
        acc[i][0] += xs * wv[kk].x;
        acc[i][1] += xs * wv[kk].y;
        acc[i][2] += xs * wv[kk].z;
        acc[i][3] += xs * wv[kk].w;
      }
    }
  }
#pragma unroll
  for (int i = 0; i < 4; ++i) {
    int r = row0 + rg + i;
    if (r < N_NODESC) {
      float s = inv[r];
      float4 o = make_float4(acc[i][0] * s, acc[i][1] * s, acc[i][2] * s, acc[i][3] * s);
      *(float4*)&Y[(size_t)r * DIMC + cg] = o;
    }
  }
}

// ---------------- aggregation: out = (sum_{src} Hs[src] + Hs[i]) * inv[i] + b ----------------
// One wave per node; lane = (colgroup, edge-slot); float4 gathers (512B/edge exact).
__global__ __launch_bounds__(256) void agg_kernel(const float* __restrict__ Hs, const float* __restrict__ inv,
                                                  const int* __restrict__ rowptr, const int* __restrict__ csr,
                                                  const float* __restrict__ bias, float* __restrict__ out,
                                                  int do_relu) {
  int node = blockIdx.x * 4 + (threadIdx.x >> 6);
  if (node >= N_NODESC) return;
  int lane = threadIdx.x & 63;
  int cg = (lane & 31) * 4;
  int slot = lane >> 5;
  int beg = rowptr[node], end = rowptr[node + 1];
  float4 acc = make_float4(0.f, 0.f, 0.f, 0.f);
  for (int e = beg + slot; e < end; e += 2) {
    int s = csr[e];
    float4 v = *(const float4*)&Hs[(size_t)s * DIMC + cg];
    acc.x += v.x; acc.y += v.y; acc.z += v.z; acc.w += v.w;
  }
  acc.x += __shfl_xor(acc.x, 32, 64);
  acc.y += __shfl_xor(acc.y, 32, 64);
  acc.z += __shfl_xor(acc.z, 32, 64);
  acc.w += __shfl_xor(acc.w, 32, 64);
  if (slot == 0) {
    float4 self = *(const float4*)&Hs[(size_t)node * DIMC + cg];
    float sc = inv[node];
    float4 b = *(const float4*)&bias[cg];
    float4 o;
    o.x = (acc.x + self.x) * sc + b.x;
    o.y = (acc.y + self.y) * sc + b.y;
    o.z = (acc.z + self.z) * sc + b.z;
    o.w = (acc.w + self.w) * sc + b.w;
    if (do_relu) {
      o.x = (o.x > 0.f) ? o.x : SLOPEF * o.x;
      o.y = (o.y > 0.f) ? o.y : SLOPEF * o.y;
      o.z = (o.z > 0.f) ? o.z : SLOPEF * o.z;
      o.w = (o.w > 0.f) ? o.w : SLOPEF * o.w;
    }
    *(float4*)&out[(size_t)node * DIMC + cg] = o;
  }
}

// ---------------- pooling ----------------
__global__ __launch_bounds__(128) void pool_kernel(const float* __restrict__ G, const int* __restrict__ batch,
                                                   float* __restrict__ psum, int* __restrict__ pcnt) {
  int t = threadIdx.x;
  int n0 = blockIdx.x * 64;
  int nend = min(n0 + 64, N_NODESC);
  int cur = batch[n0];
  float acc = 0.f;
  int c = 0;
  for (int n = n0; n < nend; ++n) {
    int b = batch[n];
    if (b != cur) {
      atomicAdd(&psum[cur * DIMC + t], acc);
      if (t == 0) atomicAdd(&pcnt[cur], c);
      acc = 0.f;
      c = 0;
      cur = b;
    }
    acc += G[(size_t)n * DIMC + t];
    c += 1;
  }
  atomicAdd(&psum[cur * DIMC + t], acc);
  if (t == 0) atomicAdd(&pcnt[cur], c);
}

__global__ __launch_bounds__(128) void mean_kernel(const float* __restrict__ psA, const int* __restrict__ pcA,
                                                   const float* __restrict__ psB, const int* __restrict__ pcB,
                                                   float* __restrict__ hA, float* __restrict__ hB) {
  int dir = blockIdx.x >> 6, g = blockIdx.x & 63, t = threadIdx.x;
  const float* ps = dir ? psB : psA;
  const int* pc = dir ? pcB : pcA;
  float* h = dir ? hB : hA;
  h[g * DIMC + t] = ps[g * DIMC + t] / (float)max(pc[g], 1);
}

// ---------------- attention (64 tokens per side) ----------------
__global__ __launch_bounds__(128) void qkv_kernel(const float* __restrict__ hA, const float* __restrict__ hB,
                                                  const float* __restrict__ Wq, const float* __restrict__ bq,
                                                  const float* __restrict__ Wk, const float* __restrict__ bk,
                                                  const float* __restrict__ Wv, const float* __restrict__ bv,
                                                  float* __restrict__ Q0, float* __restrict__ K0, float* __restrict__ V0,
                                                  float* __restrict__ Q1, float* __restrict__ K1, float* __restrict__ V1) {
  __shared__ float xs[DIMC];
  int task = blockIdx.x >> 6, r = blockIdx.x & 63, t = threadIdx.x;
  const float *X, *W, *b;
  float* Y;
  switch (task) {
    case 0: X = hA; W = Wq; b = bq; Y = Q0; break;
    case 1: X = hB; W = Wk; b = bk; Y = K0; break;
    case 2: X = hB; W = Wv; b = bv; Y = V0; break;
    case 3: X = hB; W = Wq; b = bq; Y = Q1; break;
    case 4: X = hA; W = Wk; b = bk; Y = K1; break;
    default: X = hA; W = Wv; b = bv; Y = V1; break;
  }
  xs[t] = X[r * DIMC + t];
  __syncthreads();
  float acc = b[t];
  for (int k = 0; k < DIMC; ++k) acc += xs[k] * W[k * DIMC + t];
  Y[r * DIMC + t] = acc;
}

__global__ __launch_bounds__(64) void attn_kernel(const float* __restrict__ Q0, const float* __restrict__ K0,
                                                  const float* __restrict__ V0, const float* __restrict__ Q1,
                                                  const float* __restrict__ K1, const float* __restrict__ V1,
                                                  float* __restrict__ O0, float* __restrict__ O1) {
  __shared__ float ps[64];
  int b = blockIdx.x;
  int dir = b >> 8, h = (b >> 6) & 3, q = b & 63;
  const float* Q = dir ? Q1 : Q0;
  const float* K = dir ? K1 : K0;
  const float* V = dir ? V1 : V0;
  float* O = dir ? O1 : O0;
  int k = threadIdx.x;
  const float* qp = Q + q * DIMC + h * HDC;
  const float* kp = K + k * DIMC + h * HDC;
  float s = 0.f;
#pragma unroll
  for (int d = 0; d < HDC; ++d) s += qp[d] * kp[d];
  s *= SCALEF;
  float m = s;
#pragma unroll
  for (int off = 32; off >= 1; off >>= 1) m = fmaxf(m, __shfl_xor(m, off, 64));
  float p = __expf(s - m);
  float sum = p;
#pragma unroll
  for (int off = 32; off >= 1; off >>= 1) sum += __shfl_xor(sum, off, 64);
  p /= sum;
  ps[k] = p;
  __syncthreads();
  int half = k >> 5, d = k & 31;
  float acc = 0.f;
#pragma unroll
  for (int j = 0; j < 32; ++j) {
    int kk = half * 32 + j;
    acc += ps[kk] * V[kk * DIMC + h * HDC + d];
  }
  acc += __shfl_xor(acc, 32, 64);
  if (half == 0) O[q * DIMC + h * HDC + d] = acc;
}

__device__ inline float blk_sum128(float v, float* red) {
#pragma unroll
  for (int off = 32; off >= 1; off >>= 1) v += __shfl_xor(v, off, 64);
  if ((threadIdx.x & 63) == 0) red[threadIdx.x >> 6] = v;
  __syncthreads();
  float r = red[0] + red[1];
  __syncthreads();
  return r;
}

__global__ __launch_bounds__(128) void oln_kernel(const float* __restrict__ O0, const float* __restrict__ O1,
                                                  const float* __restrict__ hA, const float* __restrict__ hB,
                                                  const float* __restrict__ Wo, const float* __restrict__ bo,
                                                  const float* __restrict__ g1, const float* __restrict__ be1,
                                                  float* __restrict__ X0, float* __restrict__ X1) {
  __shared__ float os[DIMC];
  __shared__ float red[2];
  int dir = blockIdx.x >> 6, q = blockIdx.x & 63, t = threadIdx.x;
  const float* O = dir ? O1 : O0;
  const float* xq = dir ? hB : hA;
  float* Xo = dir ? X1 : X0;
  os[t] = O[q * DIMC + t];
  __syncthreads();
  float acc = bo[t] + xq[q * DIMC + t];
  for (int k = 0; k < DIMC; ++k) acc += os[k] * Wo[k * DIMC + t];
  float mean = blk_sum128(acc, red) * (1.f / DIMC);
  float d = acc - mean;
  float var = blk_sum128(d * d, red) * (1.f / DIMC);
  Xo[q * DIMC + t] = d * rsqrtf(var + EPSF) * g1[t] + be1[t];
}

__global__ __launch_bounds__(256) void ff1_kernel(const float* __restrict__ X0, const float* __restrict__ X1,
                                                  const float* __restrict__ Wf1, const float* __restrict__ bf1,
                                                  float* __restrict__ F0, float* __restrict__ F1) {
  __shared__ float xs[DIMC];
  int dir = blockIdx.x >> 6, q = blockIdx.x & 63, t = threadIdx.x;
  const float* X = dir ? X1 : X0;
  float* F = dir ? F1 : F0;
  if (t < DIMC) xs[t] = X[q * DIMC + t];
  __syncthreads();
  float acc = bf1[t];
  for (int k = 0; k < DIMC; ++k) acc += xs[k] * Wf1[k * 256 + t];
  acc = (acc > 0.f) ? acc : SLOPEF * acc;
  F[q * 256 + t] = acc;
}

__global__ __launch_bounds__(128) void ffln_kernel(const float* __restrict__ F0, const float* __restrict__ F1,
                                                   const float* __restrict__ X0, const float* __restrict__ X1,
                                                   const float* __restrict__ Wf2, const float* __restrict__ bf2,
                                                   const float* __restrict__ g2, const float* __restrict__ be2,
                                                   float* __restrict__ Y0, float* __restrict__ Y1) {
  __shared__ float fs[256];
  __shared__ float red[2];
  int dir = blockIdx.x >> 6, q = blockIdx.x & 63, t = threadIdx.x;
  const float* F = dir ? F1 : F0;
  const float* X = dir ? X1 : X0;
  float* Y = dir ? Y1 : Y0;
  fs[t] = F[q * 256 + t];
  fs[t + 128] = F[q * 256 + t + 128];
  __syncthreads();
  float acc = bf2[t] + X[q * DIMC + t];
  for (int k = 0; k < 256; ++k) acc += fs[k] * Wf2[k * DIMC + t];
  float mean = blk_sum128(acc, red) * (1.f / DIMC);
  float d = acc - mean;
  float var = blk_sum128(d * d, red) * (1.f / DIMC);
  Y[q * DIMC + t] = d * rsqrtf(var + EPSF) * g2[t] + be2[t];
}

__global__ __launch_bounds__(128) void head_kernel(const float* __restrict__ Y0, const float* __restrict__ Y1,
                                                   const float* __restrict__ Wl1, const float* __restrict__ bl1,
                                                   const float* __restrict__ Wl2, const float* __restrict__ bl2,
                                                   float* __restrict__ out) {
  __shared__ float cs[256];
  __shared__ float red[2];
  int g = blockIdx.x, t = threadIdx.x;
  cs[t] = Y0[g * DIMC + t];
  cs[t + 128] = Y1[g * DIMC + t];
  __syncthreads();
  float acc = bl1[t];
  for (int k = 0; k < 256; ++k) acc += cs[k] * Wl1[k * DIMC + t];
  acc = fmaxf(acc, 0.f);
  float s = blk_sum128(acc * Wl2[t], red);
  if (t == 0) out[g] = s + bl2[0];
}

// ---------------- host ----------------
extern "C" void kernel_launch(void* const* d_in, const int* in_sizes, int n_in,
                              void* d_out, int out_size, void* d_ws, size_t ws_size,
                              hipStream_t stream) {
  const float* xA = (const float*)d_in[0];
  const float* xB = (const float*)d_in[1];
  const int* eiA = (const int*)d_in[2];
  const int* eiB = (const int*)d_in[3];
  const int* batA = (const int*)d_in[4];
  const int* batB = (const int*)d_in[5];
  const float* WA1 = (const float*)d_in[6];
  const float* WA2 = (const float*)d_in[7];
  const float* WB1 = (const float*)d_in[8];
  const float* WB2 = (const float*)d_in[9];
  const float* Wq = (const float*)d_in[10];
  const float* Wk = (const float*)d_in[11];
  const float* Wv = (const float*)d_in[12];
  const float* Wo = (const float*)d_in[13];
  const float* Wf1 = (const float*)d_in[14];
  const float* Wf2 = (const float*)d_in[15];
  const float* Wl1 = (const float*)d_in[16];
  const float* Wl2 = (const float*)d_in[17];
  const float* bA1 = (const float*)d_in[18];
  const float* bA2 = (const float*)d_in[19];
  const float* bB1 = (const float*)d_in[20];
  const float* bB2 = (const float*)d_in[21];
  const float* bq = (const float*)d_in[22];
  const float* bk = (const float*)d_in[23];
  const float* bv = (const float*)d_in[24];
  const float* bo = (const float*)d_in[25];
  const float* bf1 = (const float*)d_in[26];
  const float* bf2 = (const float*)d_in[27];
  const float* bl1 = (const float*)d_in[28];
  const float* bl2 = (const float*)d_in[29];
  const float* g1 = (const float*)d_in[30];
  const float* be1 = (const float*)d_in[31];
  const float* g2 = (const float*)d_in[32];
  const float* be2 = (const float*)d_in[33];

  char* base = (char*)d_ws;
  size_t off = 0;
  auto alloc = [&](size_t bytes) -> char* {
    char* r = base + off;
    off += (bytes + 255) & ~(size_t)255;
    return r;
  };
  float* h_buf = (float*)alloc((size_t)N_NODESC * DIMC * 4);
  float* g_buf = (float*)alloc((size_t)N_NODESC * DIMC * 4);
  int* csr = (int*)alloc((size_t)N_EDGESC * 4);
  int* rowptr = (int*)alloc((size_t)(N_NODESC + 1) * 4);
  float* inv = (float*)alloc((size_t)N_NODESC * 4);
  int* bsum = (int*)alloc((size_t)256 * 4);
  int* bbase = (int*)alloc((size_t)256 * 4);
  size_t zoff0 = off;
  int* cnt = (int*)alloc((size_t)N_NODESC * 4);
  int* fillc = (int*)alloc((size_t)N_NODESC * 4);
  size_t zbytes = off - zoff0;  // cnt+fill region (zeroed per side)
  size_t poff0 = off;
  float* psA = (float*)alloc(NGC * DIMC * 4);
  float* psB = (float*)alloc(NGC * DIMC * 4);
  int* pcA = (int*)alloc(NGC * 4);
  int* pcB = (int*)alloc(NGC * 4);
  size_t pbytes = off - poff0;  // pool region (zeroed once per call)
  float* mhA = (float*)alloc(NGC * DIMC * 4);
  float* mhB = (float*)alloc(NGC * DIMC * 4);
  float* Q0 = (float*)alloc(NGC * DIMC * 4);
  float* K0 = (float*)alloc(NGC * DIMC * 4);
  float* V0 = (float*)alloc(NGC * DIMC * 4);
  float* Q1 = (float*)alloc(NGC * DIMC * 4);
  float* K1 = (float*)alloc(NGC * DIMC * 4);
  float* V1 = (float*)alloc(NGC * DIMC * 4);
  float* O0 = (float*)alloc(NGC * DIMC * 4);
  float* O1 = (float*)alloc(NGC * DIMC * 4);
  float* X0 = (float*)alloc(NGC * DIMC * 4);
  float* X1 = (float*)alloc(NGC * DIMC * 4);
  float* F0 = (float*)alloc(NGC * 256 * 4);
  float* F1 = (float*)alloc(NGC * 256 * 4);
  float* Y0 = (float*)alloc(NGC * DIMC * 4);
  float* Y1 = (float*)alloc(NGC * DIMC * 4);

  hipMemsetAsync(base + poff0, 0, pbytes, stream);

  const int egrid = N_EDGESC / 256;            // 3125
  const int ggrid = (N_NODESC + BMR - 1) / BMR;  // 1563
  const int agrid = (N_NODESC + 3) / 4;          // 12500
  const int pgrid = (N_NODESC + 63) / 64;        // 782

  for (int side = 0; side < 2; ++side) {
    const float* x = side ? xB : xA;
    const int* ei = side ? eiB : eiA;
    const int* bat = side ? batB : batA;
    const float* W1 = side ? WB1 : WA1;
    const float* b1 = side ? bB1 : bA1;
    const float* W2 = side ? WB2 : WA2;
    const float* b2 = side ? bB2 : bA2;
    float* ps = side ? psB : psA;
    int* pc = side ? pcB : pcA;

    hipMemsetAsync(base + zoff0, 0, zbytes, stream);
    count_kernel<<<egrid, 256, 0, stream>>>(ei, cnt);
    degsum_kernel<<<SCAN_G, 256, 0, stream>>>(cnt, inv, bsum);
    scanb_kernel<<<1, 256, 0, stream>>>(bsum, bbase);
    rowptr_kernel<<<SCAN_G, 256, 0, stream>>>(cnt, bbase, rowptr);
    fill_kernel<<<egrid, 256, 0, stream>>>(ei, rowptr, fillc, csr);
    gemm_enc<<<ggrid, 256, 0, stream>>>(x, W1, inv, h_buf);
    agg_kernel<<<agrid, 256, 0, stream>>>(h_buf, inv, rowptr, csr, b1, g_buf, 1);
    gemm_enc<<<ggrid, 256, 0, stream>>>(g_buf, W2, inv, h_buf);
    agg_kernel<<<agrid, 256, 0, stream>>>(h_buf, inv, rowptr, csr, b2, g_buf, 0);
    pool_kernel<<<pgrid, 128, 0, stream>>>(g_buf, bat, ps, pc);
  }

  mean_kernel<<<128, 128, 0, stream>>>(psA, pcA, psB, pcB, mhA, mhB);
  qkv_kernel<<<384, 128, 0, stream>>>(mhA, mhB, Wq, bq, Wk, bk, Wv, bv, Q0, K0, V0, Q1, K1, V1);
  attn_kernel<<<512, 64, 0, stream>>>(Q0, K0, V0, Q1, K1, V1, O0, O1);
  oln_kernel<<<128, 128, 0, stream>>>(O0, O1, mhA, mhB, Wo, bo, g1, be1, X0, X1);
  ff1_kernel<<<128, 256, 0, stream>>>(X0, X1, Wf1, bf1, F0, F1);
  ffln_kernel<<<128, 128, 0, stream>>>(F0, F1, X0, X1, Wf2, bf2, g2, be2, Y0, Y1);
  head_kernel<<<64, 128, 0, stream>>>(Y0, Y1, Wl1, bl1, Wl2, bl2, (float*)d_out);
}

// Round 4
// 622.407 us; speedup vs baseline: 3.3825x; 1.0284x over previous
//
#include <hip/hip_runtime.h>

#define N_NODESC 50000
#define N_EDGESC 800000
#define DIMC 128
#define NGC 64
#define HDC 32
#define SLOPEF 0.01f
#define EPSF 1e-5f
#define SCALEF 0.17677669529663687f  // 32^-0.5
#define SCAN_G ((N_NODESC + 255) / 256)  // 196

// ---------------- CSR build ----------------
__global__ __launch_bounds__(256) void count_kernel(const int* __restrict__ ei, int* __restrict__ cnt) {
  int e = blockIdx.x * 256 + threadIdx.x;
  if (e < N_EDGESC) atomicAdd(&cnt[ei[N_EDGESC + e]], 1);
}

// per-block sum of cnt + inv[] compute
__global__ __launch_bounds__(256) void degsum_kernel(const int* __restrict__ cnt, float* __restrict__ inv,
                                                     int* __restrict__ bsum) {
  int i = blockIdx.x * 256 + threadIdx.x;
  int v = 0;
  if (i < N_NODESC) {
    v = cnt[i];
    inv[i] = rsqrtf((float)v + 1.0f);
  }
  int w = v;
#pragma unroll
  for (int off = 32; off >= 1; off >>= 1) w += __shfl_xor(w, off, 64);
  __shared__ int sd[4];
  if ((threadIdx.x & 63) == 0) sd[threadIdx.x >> 6] = w;
  __syncthreads();
  if (threadIdx.x == 0) bsum[blockIdx.x] = sd[0] + sd[1] + sd[2] + sd[3];
}

// exclusive scan of the 196 block sums (single small block)
__global__ __launch_bounds__(256) void scanb_kernel(const int* __restrict__ bsum, int* __restrict__ bbase) {
  __shared__ int sd[256];
  int t = threadIdx.x;
  int v = (t < SCAN_G) ? bsum[t] : 0;
  sd[t] = v;
  __syncthreads();
  for (int off = 1; off < 256; off <<= 1) {
    int u = (t >= off) ? sd[t - off] : 0;
    __syncthreads();
    sd[t] += u;
    __syncthreads();
  }
  bbase[t] = sd[t] - v;  // exclusive prefix
}

// rowptr[i] = bbase[blk] + intra-block exclusive prefix of cnt
__global__ __launch_bounds__(256) void rowptr_kernel(const int* __restrict__ cnt, const int* __restrict__ bbase,
                                                     int* __restrict__ rowptr) {
  __shared__ int sd[256];
  int t = threadIdx.x;
  int i = blockIdx.x * 256 + t;
  int v = (i < N_NODESC) ? cnt[i] : 0;
  sd[t] = v;
  __syncthreads();
  for (int off = 1; off < 256; off <<= 1) {
    int u = (t >= off) ? sd[t - off] : 0;
    __syncthreads();
    sd[t] += u;
    __syncthreads();
  }
  if (i < N_NODESC) rowptr[i] = bbase[blockIdx.x] + sd[t] - v;
  if (i == N_NODESC - 1) rowptr[N_NODESC] = N_EDGESC;  // all dsts in range -> total is constant
}

__global__ __launch_bounds__(256) void fill_kernel(const int* __restrict__ ei, const int* __restrict__ rowptr,
                                                   int* __restrict__ fillc, int* __restrict__ csr) {
  int e = blockIdx.x * 256 + threadIdx.x;
  if (e < N_EDGESC) {
    int s = ei[e];
    int d = ei[N_EDGESC + e];
    int pos = rowptr[d] + atomicAdd(&fillc[d], 1);
    csr[pos] = s;
  }
}

// ---------------- encoder GEMM: Y = (X @ W) * inv[row] ----------------
// 256 thr, BM=32 rows, W(64KB)+Xtile(16KB) LDS = 80KB -> 2 blocks/CU, 2 waves/SIMD.
// Per-thread 4 rows x 4 cols register tile; all LDS via ds_read_b128.
#define BMR 32
__global__ __launch_bounds__(256, 2) void gemm_enc(const float* __restrict__ X, const float* __restrict__ W,
                                                   const float* __restrict__ inv, float* __restrict__ Y) {
  __shared__ float Ws[DIMC * DIMC];   // 64 KB
  __shared__ float Xs[BMR * DIMC];    // 16 KB
  int t = threadIdx.x;
  int row0 = blockIdx.x * BMR;
#pragma unroll
  for (int i = 0; i < DIMC * DIMC; i += 1024) {
    *(float4*)&Ws[i + t * 4] = *(const float4*)&W[i + t * 4];
  }
  {
    const size_t lim = (size_t)N_NODESC * DIMC;
#pragma unroll
    for (int i = 0; i < BMR * DIMC; i += 1024) {
      int li = i + t * 4;
      size_t gi = (size_t)row0 * DIMC + li;
      float4 v = make_float4(0.f, 0.f, 0.f, 0.f);
      if (gi < lim) v = *(const float4*)&X[gi];
      *(float4*)&Xs[li] = v;
    }
  }
  __syncthreads();
  const int cg = (t & 31) * 4;   // col base (float4)
  const int rg = (t >> 5) * 4;   // row base (4 rows)
  float acc[4][4];
#pragma unroll
  for (int i = 0; i < 4; ++i)
#pragma unroll
    for (int j = 0; j < 4; ++j) acc[i][j] = 0.f;
  for (int k0 = 0; k0 < DIMC; k0 += 4) {
    float4 xv[4], wv[4];
#pragma unroll
    for (int i = 0; i < 4; ++i) xv[i] = *(const float4*)&Xs[(rg + i) * DIMC + k0];
#pragma unroll
    for (int kk = 0; kk < 4; ++kk) wv[kk] = *(const float4*)&Ws[(k0 + kk) * DIMC + cg];
#pragma unroll
    for (int i = 0; i < 4; ++i) {
      const float* xp = (const float*)&xv[i];
#pragma unroll
      for (int kk = 0; kk < 4; ++kk) {
        float xs = xp[kk];
        acc[i][0] += xs * wv[kk].x;
        acc[i][1] += xs * wv[kk].y;
        acc[i][2] += xs * wv[kk].z;
        acc[i][3] += xs * wv[kk].w;
      }
    }
  }
#pragma unroll
  for (int i = 0; i < 4; ++i) {
    int r = row0 + rg + i;
    if (r < N_NODESC) {
      float s = inv[r];
      float4 o = make_float4(acc[i][0] * s, acc[i][1] * s, acc[i][2] * s, acc[i][3] * s);
      *(float4*)&Y[(size_t)r * DIMC + cg] = o;
    }
  }
}

// ---------------- aggregation: out = (sum_{src} Hs[src] + Hs[i]) * inv[i] + b ----------------
// One wave per node; lane = (colgroup, edge-slot); float4 gathers (512B/edge exact).
// 4x unrolled edge loop: 4 independent gathers in flight per wave (latency hiding).
__global__ __launch_bounds__(256) void agg_kernel(const float* __restrict__ Hs, const float* __restrict__ inv,
                                                  const int* __restrict__ rowptr, const int* __restrict__ csr,
                                                  const float* __restrict__ bias, float* __restrict__ out,
                                                  int do_relu) {
  int node = blockIdx.x * 4 + (threadIdx.x >> 6);
  if (node >= N_NODESC) return;
  int lane = threadIdx.x & 63;
  int cg = (lane & 31) * 4;
  int slot = lane >> 5;
  int beg = rowptr[node], end = rowptr[node + 1];
  float4 acc = make_float4(0.f, 0.f, 0.f, 0.f);
  int e = beg;
  for (; e + 8 <= end; e += 8) {  // 8 edges/iter: 4 per slot, 4 gathers in flight
    int s0 = csr[e + slot];
    int s1 = csr[e + 2 + slot];
    int s2 = csr[e + 4 + slot];
    int s3 = csr[e + 6 + slot];
    float4 v0 = *(const float4*)&Hs[(size_t)s0 * DIMC + cg];
    float4 v1 = *(const float4*)&Hs[(size_t)s1 * DIMC + cg];
    float4 v2 = *(const float4*)&Hs[(size_t)s2 * DIMC + cg];
    float4 v3 = *(const float4*)&Hs[(size_t)s3 * DIMC + cg];
    acc.x += (v0.x + v1.x) + (v2.x + v3.x);
    acc.y += (v0.y + v1.y) + (v2.y + v3.y);
    acc.z += (v0.z + v1.z) + (v2.z + v3.z);
    acc.w += (v0.w + v1.w) + (v2.w + v3.w);
  }
  for (int t = e + slot; t < end; t += 2) {
    int s = csr[t];
    float4 v = *(const float4*)&Hs[(size_t)s * DIMC + cg];
    acc.x += v.x; acc.y += v.y; acc.z += v.z; acc.w += v.w;
  }
  acc.x += __shfl_xor(acc.x, 32, 64);
  acc.y += __shfl_xor(acc.y, 32, 64);
  acc.z += __shfl_xor(acc.z, 32, 64);
  acc.w += __shfl_xor(acc.w, 32, 64);
  if (slot == 0) {
    float4 self = *(const float4*)&Hs[(size_t)node * DIMC + cg];
    float sc = inv[node];
    float4 b = *(const float4*)&bias[cg];
    float4 o;
    o.x = (acc.x + self.x) * sc + b.x;
    o.y = (acc.y + self.y) * sc + b.y;
    o.z = (acc.z + self.z) * sc + b.z;
    o.w = (acc.w + self.w) * sc + b.w;
    if (do_relu) {
      o.x = (o.x > 0.f) ? o.x : SLOPEF * o.x;
      o.y = (o.y > 0.f) ? o.y : SLOPEF * o.y;
      o.z = (o.z > 0.f) ? o.z : SLOPEF * o.z;
      o.w = (o.w > 0.f) ? o.w : SLOPEF * o.w;
    }
    *(float4*)&out[(size_t)node * DIMC + cg] = o;
  }
}

// ---------------- pooling ----------------
__global__ __launch_bounds__(128) void pool_kernel(const float* __restrict__ G, const int* __restrict__ batch,
                                                   float* __restrict__ psum, int* __restrict__ pcnt) {
  int t = threadIdx.x;
  int n0 = blockIdx.x * 64;
  int nend = min(n0 + 64, N_NODESC);
  int cur = batch[n0];
  float acc = 0.f;
  int c = 0;
  for (int n = n0; n < nend; ++n) {
    int b = batch[n];
    if (b != cur) {
      atomicAdd(&psum[cur * DIMC + t], acc);
      if (t == 0) atomicAdd(&pcnt[cur], c);
      acc = 0.f;
      c = 0;
      cur = b;
    }
    acc += G[(size_t)n * DIMC + t];
    c += 1;
  }
  atomicAdd(&psum[cur * DIMC + t], acc);
  if (t == 0) atomicAdd(&pcnt[cur], c);
}

__global__ __launch_bounds__(128) void mean_kernel(const float* __restrict__ psA, const int* __restrict__ pcA,
                                                   const float* __restrict__ psB, const int* __restrict__ pcB,
                                                   float* __restrict__ hA, float* __restrict__ hB) {
  int dir = blockIdx.x >> 6, g = blockIdx.x & 63, t = threadIdx.x;
  const float* ps = dir ? psB : psA;
  const int* pc = dir ? pcB : pcA;
  float* h = dir ? hB : hA;
  h[g * DIMC + t] = ps[g * DIMC + t] / (float)max(pc[g], 1);
}

// ---------------- attention (64 tokens per side) ----------------
__global__ __launch_bounds__(128) void qkv_kernel(const float* __restrict__ hA, const float* __restrict__ hB,
                                                  const float* __restrict__ Wq, const float* __restrict__ bq,
                                                  const float* __restrict__ Wk, const float* __restrict__ bk,
                                                  const float* __restrict__ Wv, const float* __restrict__ bv,
                                                  float* __restrict__ Q0, float* __restrict__ K0, float* __restrict__ V0,
                                                  float* __restrict__ Q1, float* __restrict__ K1, float* __restrict__ V1) {
  __shared__ float xs[DIMC];
  int task = blockIdx.x >> 6, r = blockIdx.x & 63, t = threadIdx.x;
  const float *X, *W, *b;
  float* Y;
  switch (task) {
    case 0: X = hA; W = Wq; b = bq; Y = Q0; break;
    case 1: X = hB; W = Wk; b = bk; Y = K0; break;
    case 2: X = hB; W = Wv; b = bv; Y = V0; break;
    case 3: X = hB; W = Wq; b = bq; Y = Q1; break;
    case 4: X = hA; W = Wk; b = bk; Y = K1; break;
    default: X = hA; W = Wv; b = bv; Y = V1; break;
  }
  xs[t] = X[r * DIMC + t];
  __syncthreads();
  float acc = b[t];
  for (int k = 0; k < DIMC; ++k) acc += xs[k] * W[k * DIMC + t];
  Y[r * DIMC + t] = acc;
}

__global__ __launch_bounds__(64) void attn_kernel(const float* __restrict__ Q0, const float* __restrict__ K0,
                                                  const float* __restrict__ V0, const float* __restrict__ Q1,
                                                  const float* __restrict__ K1, const float* __restrict__ V1,
                                                  float* __restrict__ O0, float* __restrict__ O1) {
  __shared__ float ps[64];
  int b = blockIdx.x;
  int dir = b >> 8, h = (b >> 6) & 3, q = b & 63;
  const float* Q = dir ? Q1 : Q0;
  const float* K = dir ? K1 : K0;
  const float* V = dir ? V1 : V0;
  float* O = dir ? O1 : O0;
  int k = threadIdx.x;
  const float* qp = Q + q * DIMC + h * HDC;
  const float* kp = K + k * DIMC + h * HDC;
  float s = 0.f;
#pragma unroll
  for (int d = 0; d < HDC; ++d) s += qp[d] * kp[d];
  s *= SCALEF;
  float m = s;
#pragma unroll
  for (int off = 32; off >= 1; off >>= 1) m = fmaxf(m, __shfl_xor(m, off, 64));
  float p = __expf(s - m);
  float sum = p;
#pragma unroll
  for (int off = 32; off >= 1; off >>= 1) sum += __shfl_xor(sum, off, 64);
  p /= sum;
  ps[k] = p;
  __syncthreads();
  int half = k >> 5, d = k & 31;
  float acc = 0.f;
#pragma unroll
  for (int j = 0; j < 32; ++j) {
    int kk = half * 32 + j;
    acc += ps[kk] * V[kk * DIMC + h * HDC + d];
  }
  acc += __shfl_xor(acc, 32, 64);
  if (half == 0) O[q * DIMC + h * HDC + d] = acc;
}

__device__ inline float blk_sum128(float v, float* red) {
#pragma unroll
  for (int off = 32; off >= 1; off >>= 1) v += __shfl_xor(v, off, 64);
  if ((threadIdx.x & 63) == 0) red[threadIdx.x >> 6] = v;
  __syncthreads();
  float r = red[0] + red[1];
  __syncthreads();
  return r;
}

__global__ __launch_bounds__(128) void oln_kernel(const float* __restrict__ O0, const float* __restrict__ O1,
                                                  const float* __restrict__ hA, const float* __restrict__ hB,
                                                  const float* __restrict__ Wo, const float* __restrict__ bo,
                                                  const float* __restrict__ g1, const float* __restrict__ be1,
                                                  float* __restrict__ X0, float* __restrict__ X1) {
  __shared__ float os[DIMC];
  __shared__ float red[2];
  int dir = blockIdx.x >> 6, q = blockIdx.x & 63, t = threadIdx.x;
  const float* O = dir ? O1 : O0;
  const float* xq = dir ? hB : hA;
  float* Xo = dir ? X1 : X0;
  os[t] = O[q * DIMC + t];
  __syncthreads();
  float acc = bo[t] + xq[q * DIMC + t];
  for (int k = 0; k < DIMC; ++k) acc += os[k] * Wo[k * DIMC + t];
  float mean = blk_sum128(acc, red) * (1.f / DIMC);
  float d = acc - mean;
  float var = blk_sum128(d * d, red) * (1.f / DIMC);
  Xo[q * DIMC + t] = d * rsqrtf(var + EPSF) * g1[t] + be1[t];
}

__global__ __launch_bounds__(256) void ff1_kernel(const float* __restrict__ X0, const float* __restrict__ X1,
                                                  const float* __restrict__ Wf1, const float* __restrict__ bf1,
                                                  float* __restrict__ F0, float* __restrict__ F1) {
  __shared__ float xs[DIMC];
  int dir = blockIdx.x >> 6, q = blockIdx.x & 63, t = threadIdx.x;
  const float* X = dir ? X1 : X0;
  float* F = dir ? F1 : F0;
  if (t < DIMC) xs[t] = X[q * DIMC + t];
  __syncthreads();
  float acc = bf1[t];
  for (int k = 0; k < DIMC; ++k) acc += xs[k] * Wf1[k * 256 + t];
  acc = (acc > 0.f) ? acc : SLOPEF * acc;
  F[q * 256 + t] = acc;
}

__global__ __launch_bounds__(128) void ffln_kernel(const float* __restrict__ F0, const float* __restrict__ F1,
                                                   const float* __restrict__ X0, const float* __restrict__ X1,
                                                   const float* __restrict__ Wf2, const float* __restrict__ bf2,
                                                   const float* __restrict__ g2, const float* __restrict__ be2,
                                                   float* __restrict__ Y0, float* __restrict__ Y1) {
  __shared__ float fs[256];
  __shared__ float red[2];
  int dir = blockIdx.x >> 6, q = blockIdx.x & 63, t = threadIdx.x;
  const float* F = dir ? F1 : F0;
  const float* X = dir ? X1 : X0;
  float* Y = dir ? Y1 : Y0;
  fs[t] = F[q * 256 + t];
  fs[t + 128] = F[q * 256 + t + 128];
  __syncthreads();
  float acc = bf2[t] + X[q * DIMC + t];
  for (int k = 0; k < 256; ++k) acc += fs[k] * Wf2[k * DIMC + t];
  float mean = blk_sum128(acc, red) * (1.f / DIMC);
  float d = acc - mean;
  float var = blk_sum128(d * d, red) * (1.f / DIMC);
  Y[q * DIMC + t] = d * rsqrtf(var + EPSF) * g2[t] + be2[t];
}

__global__ __launch_bounds__(128) void head_kernel(const float* __restrict__ Y0, const float* __restrict__ Y1,
                                                   const float* __restrict__ Wl1, const float* __restrict__ bl1,
                                                   const float* __restrict__ Wl2, const float* __restrict__ bl2,
                                                   float* __restrict__ out) {
  __shared__ float cs[256];
  __shared__ float red[2];
  int g = blockIdx.x, t = threadIdx.x;
  cs[t] = Y0[g * DIMC + t];
  cs[t + 128] = Y1[g * DIMC + t];
  __syncthreads();
  float acc = bl1[t];
  for (int k = 0; k < 256; ++k) acc += cs[k] * Wl1[k * DIMC + t];
  acc = fmaxf(acc, 0.f);
  float s = blk_sum128(acc * Wl2[t], red);
  if (t == 0) out[g] = s + bl2[0];
}

// ---------------- host ----------------
extern "C" void kernel_launch(void* const* d_in, const int* in_sizes, int n_in,
                              void* d_out, int out_size, void* d_ws, size_t ws_size,
                              hipStream_t stream) {
  const float* xA = (const float*)d_in[0];
  const float* xB = (const float*)d_in[1];
  const int* eiA = (const int*)d_in[2];
  const int* eiB = (const int*)d_in[3];
  const int* batA = (const int*)d_in[4];
  const int* batB = (const int*)d_in[5];
  const float* WA1 = (const float*)d_in[6];
  const float* WA2 = (const float*)d_in[7];
  const float* WB1 = (const float*)d_in[8];
  const float* WB2 = (const float*)d_in[9];
  const float* Wq = (const float*)d_in[10];
  const float* Wk = (const float*)d_in[11];
  const float* Wv = (const float*)d_in[12];
  const float* Wo = (const float*)d_in[13];
  const float* Wf1 = (const float*)d_in[14];
  const float* Wf2 = (const float*)d_in[15];
  const float* Wl1 = (const float*)d_in[16];
  const float* Wl2 = (const float*)d_in[17];
  const float* bA1 = (const float*)d_in[18];
  const float* bA2 = (const float*)d_in[19];
  const float* bB1 = (const float*)d_in[20];
  const float* bB2 = (const float*)d_in[21];
  const float* bq = (const float*)d_in[22];
  const float* bk = (const float*)d_in[23];
  const float* bv = (const float*)d_in[24];
  const float* bo = (const float*)d_in[25];
  const float* bf1 = (const float*)d_in[26];
  const float* bf2 = (const float*)d_in[27];
  const float* bl1 = (const float*)d_in[28];
  const float* bl2 = (const float*)d_in[29];
  const float* g1 = (const float*)d_in[30];
  const float* be1 = (const float*)d_in[31];
  const float* g2 = (const float*)d_in[32];
  const float* be2 = (const float*)d_in[33];

  char* base = (char*)d_ws;
  size_t off = 0;
  auto alloc = [&](size_t bytes) -> char* {
    char* r = base + off;
    off += (bytes + 255) & ~(size_t)255;
    return r;
  };
  float* h_buf = (float*)alloc((size_t)N_NODESC * DIMC * 4);
  float* g_buf = (float*)alloc((size_t)N_NODESC * DIMC * 4);
  int* csr = (int*)alloc((size_t)N_EDGESC * 4);
  int* rowptr = (int*)alloc((size_t)(N_NODESC + 1) * 4);
  float* inv = (float*)alloc((size_t)N_NODESC * 4);
  int* bsum = (int*)alloc((size_t)256 * 4);
  int* bbase = (int*)alloc((size_t)256 * 4);
  size_t zoff0 = off;
  int* cnt = (int*)alloc((size_t)N_NODESC * 4);
  int* fillc = (int*)alloc((size_t)N_NODESC * 4);
  size_t zbytes = off - zoff0;  // cnt+fill region (zeroed per side)
  size_t poff0 = off;
  float* psA = (float*)alloc(NGC * DIMC * 4);
  float* psB = (float*)alloc(NGC * DIMC * 4);
  int* pcA = (int*)alloc(NGC * 4);
  int* pcB = (int*)alloc(NGC * 4);
  size_t pbytes = off - poff0;  // pool region (zeroed once per call)
  float* mhA = (float*)alloc(NGC * DIMC * 4);
  float* mhB = (float*)alloc(NGC * DIMC * 4);
  float* Q0 = (float*)alloc(NGC * DIMC * 4);
  float* K0 = (float*)alloc(NGC * DIMC * 4);
  float* V0 = (float*)alloc(NGC * DIMC * 4);
  float* Q1 = (float*)alloc(NGC * DIMC * 4);
  float* K1 = (float*)alloc(NGC * DIMC * 4);
  float* V1 = (float*)alloc(NGC * DIMC * 4);
  float* O0 = (float*)alloc(NGC * DIMC * 4);
  float* O1 = (float*)alloc(NGC * DIMC * 4);
  float* X0 = (float*)alloc(NGC * DIMC * 4);
  float* X1 = (float*)alloc(NGC * DIMC * 4);
  float* F0 = (float*)alloc(NGC * 256 * 4);
  float* F1 = (float*)alloc(NGC * 256 * 4);
  float* Y0 = (float*)alloc(NGC * DIMC * 4);
  float* Y1 = (float*)alloc(NGC * DIMC * 4);

  hipMemsetAsync(base + poff0, 0, pbytes, stream);

  const int egrid = N_EDGESC / 256;            // 3125
  const int ggrid = (N_NODESC + BMR - 1) / BMR;  // 1563
  const int agrid = (N_NODESC + 3) / 4;          // 12500
  const int pgrid = (N_NODESC + 63) / 64;        // 782

  for (int side = 0; side < 2; ++side) {
    const float* x = side ? xB : xA;
    const int* ei = side ? eiB : eiA;
    const int* bat = side ? batB : batA;
    const float* W1 = side ? WB1 : WA1;
    const float* b1 = side ? bB1 : bA1;
    const float* W2 = side ? WB2 : WA2;
    const float* b2 = side ? bB2 : bA2;
    float* ps = side ? psB : psA;
    int* pc = side ? pcB : pcA;

    hipMemsetAsync(base + zoff0, 0, zbytes, stream);
    count_kernel<<<egrid, 256, 0, stream>>>(ei, cnt);
    degsum_kernel<<<SCAN_G, 256, 0, stream>>>(cnt, inv, bsum);
    scanb_kernel<<<1, 256, 0, stream>>>(bsum, bbase);
    rowptr_kernel<<<SCAN_G, 256, 0, stream>>>(cnt, bbase, rowptr);
    fill_kernel<<<egrid, 256, 0, stream>>>(ei, rowptr, fillc, csr);
    gemm_enc<<<ggrid, 256, 0, stream>>>(x, W1, inv, h_buf);
    agg_kernel<<<agrid, 256, 0, stream>>>(h_buf, inv, rowptr, csr, b1, g_buf, 1);
    gemm_enc<<<ggrid, 256, 0, stream>>>(g_buf, W2, inv, h_buf);
    agg_kernel<<<agrid, 256, 0, stream>>>(h_buf, inv, rowptr, csr, b2, g_buf, 0);
    pool_kernel<<<pgrid, 128, 0, stream>>>(g_buf, bat, ps, pc);
  }

  mean_kernel<<<128, 128, 0, stream>>>(psA, pcA, psB, pcB, mhA, mhB);
  qkv_kernel<<<384, 128, 0, stream>>>(mhA, mhB, Wq, bq, Wk, bk, Wv, bv, Q0, K0, V0, Q1, K1, V1);
  attn_kernel<<<512, 64, 0, stream>>>(Q0, K0, V0, Q1, K1, V1, O0, O1);
  oln_kernel<<<128, 128, 0, stream>>>(O0, O1, mhA, mhB, Wo, bo, g1, be1, X0, X1);
  ff1_kernel<<<128, 256, 0, stream>>>(X0, X1, Wf1, bf1, F0, F1);
  ffln_kernel<<<128, 128, 0, stream>>>(F0, F1, X0, X1, Wf2, bf2, g2, be2, Y0, Y1);
  head_kernel<<<64, 128, 0, stream>>>(Y0, Y1, Wl1, bl1, Wl2, bl2, (float*)d_out);
}

// Round 5
// 531.297 us; speedup vs baseline: 3.9625x; 1.1715x over previous
//
#include <hip/hip_runtime.h>

#define N_NODESC 50000
#define N_EDGESC 800000
#define DIMC 128
#define NGC 64
#define HDC 32
#define SLOPEF 0.01f
#define EPSF 1e-5f
#define SCALEF 0.17677669529663687f  // 32^-0.5
#define SCAN_G ((N_NODESC + 255) / 256)  // 196

// fp32 <-> bf16 (RNE)
static __device__ __forceinline__ unsigned short f2bf(float f) {
  unsigned u = __float_as_uint(f);
  u = u + 0x7FFFu + ((u >> 16) & 1u);
  return (unsigned short)(u >> 16);
}
static __device__ __forceinline__ float bf2f(unsigned short h) {
  return __uint_as_float(((unsigned)h) << 16);
}

// ---------------- CSR build ----------------
__global__ __launch_bounds__(256) void count_kernel(const int* __restrict__ ei, int* __restrict__ cnt) {
  int e = blockIdx.x * 256 + threadIdx.x;
  if (e < N_EDGESC) atomicAdd(&cnt[ei[N_EDGESC + e]], 1);
}

// per-block sum of cnt + inv[] compute
__global__ __launch_bounds__(256) void degsum_kernel(const int* __restrict__ cnt, float* __restrict__ inv,
                                                     int* __restrict__ bsum) {
  int i = blockIdx.x * 256 + threadIdx.x;
  int v = 0;
  if (i < N_NODESC) {
    v = cnt[i];
    inv[i] = rsqrtf((float)v + 1.0f);
  }
  int w = v;
#pragma unroll
  for (int off = 32; off >= 1; off >>= 1) w += __shfl_xor(w, off, 64);
  __shared__ int sd[4];
  if ((threadIdx.x & 63) == 0) sd[threadIdx.x >> 6] = w;
  __syncthreads();
  if (threadIdx.x == 0) bsum[blockIdx.x] = sd[0] + sd[1] + sd[2] + sd[3];
}

// exclusive scan of the 196 block sums (single small block)
__global__ __launch_bounds__(256) void scanb_kernel(const int* __restrict__ bsum, int* __restrict__ bbase) {
  __shared__ int sd[256];
  int t = threadIdx.x;
  int v = (t < SCAN_G) ? bsum[t] : 0;
  sd[t] = v;
  __syncthreads();
  for (int off = 1; off < 256; off <<= 1) {
    int u = (t >= off) ? sd[t - off] : 0;
    __syncthreads();
    sd[t] += u;
    __syncthreads();
  }
  bbase[t] = sd[t] - v;  // exclusive prefix
}

// rowptr[i] = bbase[blk] + intra-block exclusive prefix of cnt
__global__ __launch_bounds__(256) void rowptr_kernel(const int* __restrict__ cnt, const int* __restrict__ bbase,
                                                     int* __restrict__ rowptr) {
  __shared__ int sd[256];
  int t = threadIdx.x;
  int i = blockIdx.x * 256 + t;
  int v = (i < N_NODESC) ? cnt[i] : 0;
  sd[t] = v;
  __syncthreads();
  for (int off = 1; off < 256; off <<= 1) {
    int u = (t >= off) ? sd[t - off] : 0;
    __syncthreads();
    sd[t] += u;
    __syncthreads();
  }
  if (i < N_NODESC) rowptr[i] = bbase[blockIdx.x] + sd[t] - v;
  if (i == N_NODESC - 1) rowptr[N_NODESC] = N_EDGESC;  // all dsts in range -> total is constant
}

__global__ __launch_bounds__(256) void fill_kernel(const int* __restrict__ ei, const int* __restrict__ rowptr,
                                                   int* __restrict__ fillc, int* __restrict__ csr) {
  int e = blockIdx.x * 256 + threadIdx.x;
  if (e < N_EDGESC) {
    int s = ei[e];
    int d = ei[N_EDGESC + e];
    int pos = rowptr[d] + atomicAdd(&fillc[d], 1);
    csr[pos] = s;
  }
}

// ---------------- encoder GEMM: Y(bf16) = (X @ W) * inv[row] ----------------
// 256 thr, BM=32 rows, W(64KB)+Xtile(16KB) LDS = 80KB -> 2 blocks/CU.
#define BMR 32
__global__ __launch_bounds__(256, 2) void gemm_enc(const float* __restrict__ X, const float* __restrict__ W,
                                                   const float* __restrict__ inv, unsigned short* __restrict__ Y) {
  __shared__ float Ws[DIMC * DIMC];   // 64 KB
  __shared__ float Xs[BMR * DIMC];    // 16 KB
  int t = threadIdx.x;
  int row0 = blockIdx.x * BMR;
#pragma unroll
  for (int i = 0; i < DIMC * DIMC; i += 1024) {
    *(float4*)&Ws[i + t * 4] = *(const float4*)&W[i + t * 4];
  }
  {
    const size_t lim = (size_t)N_NODESC * DIMC;
#pragma unroll
    for (int i = 0; i < BMR * DIMC; i += 1024) {
      int li = i + t * 4;
      size_t gi = (size_t)row0 * DIMC + li;
      float4 v = make_float4(0.f, 0.f, 0.f, 0.f);
      if (gi < lim) v = *(const float4*)&X[gi];
      *(float4*)&Xs[li] = v;
    }
  }
  __syncthreads();
  const int cg = (t & 31) * 4;   // col base (4 cols)
  const int rg = (t >> 5) * 4;   // row base (4 rows)
  float acc[4][4];
#pragma unroll
  for (int i = 0; i < 4; ++i)
#pragma unroll
    for (int j = 0; j < 4; ++j) acc[i][j] = 0.f;
  for (int k0 = 0; k0 < DIMC; k0 += 4) {
    float4 xv[4], wv[4];
#pragma unroll
    for (int i = 0; i < 4; ++i) xv[i] = *(const float4*)&Xs[(rg + i) * DIMC + k0];
#pragma unroll
    for (int kk = 0; kk < 4; ++kk) wv[kk] = *(const float4*)&Ws[(k0 + kk) * DIMC + cg];
#pragma unroll
    for (int i = 0; i < 4; ++i) {
      const float* xp = (const float*)&xv[i];
#pragma unroll
      for (int kk = 0; kk < 4; ++kk) {
        float xs = xp[kk];
        acc[i][0] += xs * wv[kk].x;
        acc[i][1] += xs * wv[kk].y;
        acc[i][2] += xs * wv[kk].z;
        acc[i][3] += xs * wv[kk].w;
      }
    }
  }
#pragma unroll
  for (int i = 0; i < 4; ++i) {
    int r = row0 + rg + i;
    if (r < N_NODESC) {
      float s = inv[r];
      ushort4 o;
      o.x = f2bf(acc[i][0] * s);
      o.y = f2bf(acc[i][1] * s);
      o.z = f2bf(acc[i][2] * s);
      o.w = f2bf(acc[i][3] * s);
      *(ushort4*)&Y[(size_t)r * DIMC + cg] = o;
    }
  }
}

// ---------------- aggregation: out = (sum_{src} Hs[src] + Hs[i]) * inv[i] + b ----------------
// Hs is bf16 (256B rows); one wave per node; lane = (colgroup, edge-slot); ushort4 gathers (8B/lane).
__global__ __launch_bounds__(256) void agg_kernel(const unsigned short* __restrict__ Hs, const float* __restrict__ inv,
                                                  const int* __restrict__ rowptr, const int* __restrict__ csr,
                                                  const float* __restrict__ bias, float* __restrict__ out,
                                                  int do_relu) {
  int node = blockIdx.x * 4 + (threadIdx.x >> 6);
  if (node >= N_NODESC) return;
  int lane = threadIdx.x & 63;
  int cg = (lane & 31) * 4;
  int slot = lane >> 5;
  int beg = rowptr[node], end = rowptr[node + 1];
  float4 acc = make_float4(0.f, 0.f, 0.f, 0.f);
  int e = beg;
  for (; e + 8 <= end; e += 8) {  // 8 edges/iter: 4 per slot, 4 gathers in flight
    int s0 = csr[e + slot];
    int s1 = csr[e + 2 + slot];
    int s2 = csr[e + 4 + slot];
    int s3 = csr[e + 6 + slot];
    ushort4 v0 = *(const ushort4*)&Hs[(size_t)s0 * DIMC + cg];
    ushort4 v1 = *(const ushort4*)&Hs[(size_t)s1 * DIMC + cg];
    ushort4 v2 = *(const ushort4*)&Hs[(size_t)s2 * DIMC + cg];
    ushort4 v3 = *(const ushort4*)&Hs[(size_t)s3 * DIMC + cg];
    acc.x += (bf2f(v0.x) + bf2f(v1.x)) + (bf2f(v2.x) + bf2f(v3.x));
    acc.y += (bf2f(v0.y) + bf2f(v1.y)) + (bf2f(v2.y) + bf2f(v3.y));
    acc.z += (bf2f(v0.z) + bf2f(v1.z)) + (bf2f(v2.z) + bf2f(v3.z));
    acc.w += (bf2f(v0.w) + bf2f(v1.w)) + (bf2f(v2.w) + bf2f(v3.w));
  }
  for (int t = e + slot; t < end; t += 2) {
    int s = csr[t];
    ushort4 v = *(const ushort4*)&Hs[(size_t)s * DIMC + cg];
    acc.x += bf2f(v.x); acc.y += bf2f(v.y); acc.z += bf2f(v.z); acc.w += bf2f(v.w);
  }
  acc.x += __shfl_xor(acc.x, 32, 64);
  acc.y += __shfl_xor(acc.y, 32, 64);
  acc.z += __shfl_xor(acc.z, 32, 64);
  acc.w += __shfl_xor(acc.w, 32, 64);
  if (slot == 0) {
    ushort4 sv = *(const ushort4*)&Hs[(size_t)node * DIMC + cg];
    float sc = inv[node];
    float4 b = *(const float4*)&bias[cg];
    float4 o;
    o.x = (acc.x + bf2f(sv.x)) * sc + b.x;
    o.y = (acc.y + bf2f(sv.y)) * sc + b.y;
    o.z = (acc.z + bf2f(sv.z)) * sc + b.z;
    o.w = (acc.w + bf2f(sv.w)) * sc + b.w;
    if (do_relu) {
      o.x = (o.x > 0.f) ? o.x : SLOPEF * o.x;
      o.y = (o.y > 0.f) ? o.y : SLOPEF * o.y;
      o.z = (o.z > 0.f) ? o.z : SLOPEF * o.z;
      o.w = (o.w > 0.f) ? o.w : SLOPEF * o.w;
    }
    *(float4*)&out[(size_t)node * DIMC + cg] = o;
  }
}

// ---------------- pooling ----------------
__global__ __launch_bounds__(128) void pool_kernel(const float* __restrict__ G, const int* __restrict__ batch,
                                                   float* __restrict__ psum, int* __restrict__ pcnt) {
  int t = threadIdx.x;
  int n0 = blockIdx.x * 64;
  int nend = min(n0 + 64, N_NODESC);
  int cur = batch[n0];
  float acc = 0.f;
  int c = 0;
  for (int n = n0; n < nend; ++n) {
    int b = batch[n];
    if (b != cur) {
      atomicAdd(&psum[cur * DIMC + t], acc);
      if (t == 0) atomicAdd(&pcnt[cur], c);
      acc = 0.f;
      c = 0;
      cur = b;
    }
    acc += G[(size_t)n * DIMC + t];
    c += 1;
  }
  atomicAdd(&psum[cur * DIMC + t], acc);
  if (t == 0) atomicAdd(&pcnt[cur], c);
}

__global__ __launch_bounds__(128) void mean_kernel(const float* __restrict__ psA, const int* __restrict__ pcA,
                                                   const float* __restrict__ psB, const int* __restrict__ pcB,
                                                   float* __restrict__ hA, float* __restrict__ hB) {
  int dir = blockIdx.x >> 6, g = blockIdx.x & 63, t = threadIdx.x;
  const float* ps = dir ? psB : psA;
  const int* pc = dir ? pcB : pcA;
  float* h = dir ? hB : hA;
  h[g * DIMC + t] = ps[g * DIMC + t] / (float)max(pc[g], 1);
}

// ---------------- attention (64 tokens per side) ----------------
__global__ __launch_bounds__(128) void qkv_kernel(const float* __restrict__ hA, const float* __restrict__ hB,
                                                  const float* __restrict__ Wq, const float* __restrict__ bq,
                                                  const float* __restrict__ Wk, const float* __restrict__ bk,
                                                  const float* __restrict__ Wv, const float* __restrict__ bv,
                                                  float* __restrict__ Q0, float* __restrict__ K0, float* __restrict__ V0,
                                                  float* __restrict__ Q1, float* __restrict__ K1, float* __restrict__ V1) {
  __shared__ float xs[DIMC];
  int task = blockIdx.x >> 6, r = blockIdx.x & 63, t = threadIdx.x;
  const float *X, *W, *b;
  float* Y;
  switch (task) {
    case 0: X = hA; W = Wq; b = bq; Y = Q0; break;
    case 1: X = hB; W = Wk; b = bk; Y = K0; break;
    case 2: X = hB; W = Wv; b = bv; Y = V0; break;
    case 3: X = hB; W = Wq; b = bq; Y = Q1; break;
    case 4: X = hA; W = Wk; b = bk; Y = K1; break;
    default: X = hA; W = Wv; b = bv; Y = V1; break;
  }
  xs[t] = X[r * DIMC + t];
  __syncthreads();
  float acc = b[t];
  for (int k = 0; k < DIMC; ++k) acc += xs[k] * W[k * DIMC + t];
  Y[r * DIMC + t] = acc;
}

__global__ __launch_bounds__(64) void attn_kernel(const float* __restrict__ Q0, const float* __restrict__ K0,
                                                  const float* __restrict__ V0, const float* __restrict__ Q1,
                                                  const float* __restrict__ K1, const float* __restrict__ V1,
                                                  float* __restrict__ O0, float* __restrict__ O1) {
  __shared__ float ps[64];
  int b = blockIdx.x;
  int dir = b >> 8, h = (b >> 6) & 3, q = b & 63;
  const float* Q = dir ? Q1 : Q0;
  const float* K = dir ? K1 : K0;
  const float* V = dir ? V1 : V0;
  float* O = dir ? O1 : O0;
  int k = threadIdx.x;
  const float* qp = Q + q * DIMC + h * HDC;
  const float* kp = K + k * DIMC + h * HDC;
  float s = 0.f;
#pragma unroll
  for (int d = 0; d < HDC; ++d) s += qp[d] * kp[d];
  s *= SCALEF;
  float m = s;
#pragma unroll
  for (int off = 32; off >= 1; off >>= 1) m = fmaxf(m, __shfl_xor(m, off, 64));
  float p = __expf(s - m);
  float sum = p;
#pragma unroll
  for (int off = 32; off >= 1; off >>= 1) sum += __shfl_xor(sum, off, 64);
  p /= sum;
  ps[k] = p;
  __syncthreads();
  int half = k >> 5, d = k & 31;
  float acc = 0.f;
#pragma unroll
  for (int j = 0; j < 32; ++j) {
    int kk = half * 32 + j;
    acc += ps[kk] * V[kk * DIMC + h * HDC + d];
  }
  acc += __shfl_xor(acc, 32, 64);
  if (half == 0) O[q * DIMC + h * HDC + d] = acc;
}

__device__ inline float blk_sum128(float v, float* red) {
#pragma unroll
  for (int off = 32; off >= 1; off >>= 1) v += __shfl_xor(v, off, 64);
  if ((threadIdx.x & 63) == 0) red[threadIdx.x >> 6] = v;
  __syncthreads();
  float r = red[0] + red[1];
  __syncthreads();
  return r;
}

__global__ __launch_bounds__(128) void oln_kernel(const float* __restrict__ O0, const float* __restrict__ O1,
                                                  const float* __restrict__ hA, const float* __restrict__ hB,
                                                  const float* __restrict__ Wo, const float* __restrict__ bo,
                                                  const float* __restrict__ g1, const float* __restrict__ be1,
                                                  float* __restrict__ X0, float* __restrict__ X1) {
  __shared__ float os[DIMC];
  __shared__ float red[2];
  int dir = blockIdx.x >> 6, q = blockIdx.x & 63, t = threadIdx.x;
  const float* O = dir ? O1 : O0;
  const float* xq = dir ? hB : hA;
  float* Xo = dir ? X1 : X0;
  os[t] = O[q * DIMC + t];
  __syncthreads();
  float acc = bo[t] + xq[q * DIMC + t];
  for (int k = 0; k < DIMC; ++k) acc += os[k] * Wo[k * DIMC + t];
  float mean = blk_sum128(acc, red) * (1.f / DIMC);
  float d = acc - mean;
  float var = blk_sum128(d * d, red) * (1.f / DIMC);
  Xo[q * DIMC + t] = d * rsqrtf(var + EPSF) * g1[t] + be1[t];
}

__global__ __launch_bounds__(256) void ff1_kernel(const float* __restrict__ X0, const float* __restrict__ X1,
                                                  const float* __restrict__ Wf1, const float* __restrict__ bf1,
                                                  float* __restrict__ F0, float* __restrict__ F1) {
  __shared__ float xs[DIMC];
  int dir = blockIdx.x >> 6, q = blockIdx.x & 63, t = threadIdx.x;
  const float* X = dir ? X1 : X0;
  float* F = dir ? F1 : F0;
  if (t < DIMC) xs[t] = X[q * DIMC + t];
  __syncthreads();
  float acc = bf1[t];
  for (int k = 0; k < DIMC; ++k) acc += xs[k] * Wf1[k * 256 + t];
  acc = (acc > 0.f) ? acc : SLOPEF * acc;
  F[q * 256 + t] = acc;
}

__global__ __launch_bounds__(128) void ffln_kernel(const float* __restrict__ F0, const float* __restrict__ F1,
                                                   const float* __restrict__ X0, const float* __restrict__ X1,
                                                   const float* __restrict__ Wf2, const float* __restrict__ bf2,
                                                   const float* __restrict__ g2, const float* __restrict__ be2,
                                                   float* __restrict__ Y0, float* __restrict__ Y1) {
  __shared__ float fs[256];
  __shared__ float red[2];
  int dir = blockIdx.x >> 6, q = blockIdx.x & 63, t = threadIdx.x;
  const float* F = dir ? F1 : F0;
  const float* X = dir ? X1 : X0;
  float* Y = dir ? Y1 : Y0;
  fs[t] = F[q * 256 + t];
  fs[t + 128] = F[q * 256 + t + 128];
  __syncthreads();
  float acc = bf2[t] + X[q * DIMC + t];
  for (int k = 0; k < 256; ++k) acc += fs[k] * Wf2[k * DIMC + t];
  float mean = blk_sum128(acc, red) * (1.f / DIMC);
  float d = acc - mean;
  float var = blk_sum128(d * d, red) * (1.f / DIMC);
  Y[q * DIMC + t] = d * rsqrtf(var + EPSF) * g2[t] + be2[t];
}

__global__ __launch_bounds__(128) void head_kernel(const float* __restrict__ Y0, const float* __restrict__ Y1,
                                                   const float* __restrict__ Wl1, const float* __restrict__ bl1,
                                                   const float* __restrict__ Wl2, const float* __restrict__ bl2,
                                                   float* __restrict__ out) {
  __shared__ float cs[256];
  __shared__ float red[2];
  int g = blockIdx.x, t = threadIdx.x;
  cs[t] = Y0[g * DIMC + t];
  cs[t + 128] = Y1[g * DIMC + t];
  __syncthreads();
  float acc = bl1[t];
  for (int k = 0; k < 256; ++k) acc += cs[k] * Wl1[k * DIMC + t];
  acc = fmaxf(acc, 0.f);
  float s = blk_sum128(acc * Wl2[t], red);
  if (t == 0) out[g] = s + bl2[0];
}

// ---------------- host ----------------
extern "C" void kernel_launch(void* const* d_in, const int* in_sizes, int n_in,
                              void* d_out, int out_size, void* d_ws, size_t ws_size,
                              hipStream_t stream) {
  const float* xA = (const float*)d_in[0];
  const float* xB = (const float*)d_in[1];
  const int* eiA = (const int*)d_in[2];
  const int* eiB = (const int*)d_in[3];
  const int* batA = (const int*)d_in[4];
  const int* batB = (const int*)d_in[5];
  const float* WA1 = (const float*)d_in[6];
  const float* WA2 = (const float*)d_in[7];
  const float* WB1 = (const float*)d_in[8];
  const float* WB2 = (const float*)d_in[9];
  const float* Wq = (const float*)d_in[10];
  const float* Wk = (const float*)d_in[11];
  const float* Wv = (const float*)d_in[12];
  const float* Wo = (const float*)d_in[13];
  const float* Wf1 = (const float*)d_in[14];
  const float* Wf2 = (const float*)d_in[15];
  const float* Wl1 = (const float*)d_in[16];
  const float* Wl2 = (const float*)d_in[17];
  const float* bA1 = (const float*)d_in[18];
  const float* bA2 = (const float*)d_in[19];
  const float* bB1 = (const float*)d_in[20];
  const float* bB2 = (const float*)d_in[21];
  const float* bq = (const float*)d_in[22];
  const float* bk = (const float*)d_in[23];
  const float* bv = (const float*)d_in[24];
  const float* bo = (const float*)d_in[25];
  const float* bf1 = (const float*)d_in[26];
  const float* bf2 = (const float*)d_in[27];
  const float* bl1 = (const float*)d_in[28];
  const float* bl2 = (const float*)d_in[29];
  const float* g1 = (const float*)d_in[30];
  const float* be1 = (const float*)d_in[31];
  const float* g2 = (const float*)d_in[32];
  const float* be2 = (const float*)d_in[33];

  char* base = (char*)d_ws;
  size_t off = 0;
  auto alloc = [&](size_t bytes) -> char* {
    char* r = base + off;
    off += (bytes + 255) & ~(size_t)255;
    return r;
  };
  unsigned short* h_buf = (unsigned short*)alloc((size_t)N_NODESC * DIMC * 2);  // bf16
  float* g_buf = (float*)alloc((size_t)N_NODESC * DIMC * 4);
  int* csr = (int*)alloc((size_t)N_EDGESC * 4);
  int* rowptr = (int*)alloc((size_t)(N_NODESC + 1) * 4);
  float* inv = (float*)alloc((size_t)N_NODESC * 4);
  int* bsum = (int*)alloc((size_t)256 * 4);
  int* bbase = (int*)alloc((size_t)256 * 4);
  size_t zoff0 = off;
  int* cnt = (int*)alloc((size_t)N_NODESC * 4);
  int* fillc = (int*)alloc((size_t)N_NODESC * 4);
  size_t zbytes = off - zoff0;  // cnt+fill region (zeroed per side)
  size_t poff0 = off;
  float* psA = (float*)alloc(NGC * DIMC * 4);
  float* psB = (float*)alloc(NGC * DIMC * 4);
  int* pcA = (int*)alloc(NGC * 4);
  int* pcB = (int*)alloc(NGC * 4);
  size_t pbytes = off - poff0;  // pool region (zeroed once per call)
  float* mhA = (float*)alloc(NGC * DIMC * 4);
  float* mhB = (float*)alloc(NGC * DIMC * 4);
  float* Q0 = (float*)alloc(NGC * DIMC * 4);
  float* K0 = (float*)alloc(NGC * DIMC * 4);
  float* V0 = (float*)alloc(NGC * DIMC * 4);
  float* Q1 = (float*)alloc(NGC * DIMC * 4);
  float* K1 = (float*)alloc(NGC * DIMC * 4);
  float* V1 = (float*)alloc(NGC * DIMC * 4);
  float* O0 = (float*)alloc(NGC * DIMC * 4);
  float* O1 = (float*)alloc(NGC * DIMC * 4);
  float* X0 = (float*)alloc(NGC * DIMC * 4);
  float* X1 = (float*)alloc(NGC * DIMC * 4);
  float* F0 = (float*)alloc(NGC * 256 * 4);
  float* F1 = (float*)alloc(NGC * 256 * 4);
  float* Y0 = (float*)alloc(NGC * DIMC * 4);
  float* Y1 = (float*)alloc(NGC * DIMC * 4);

  hipMemsetAsync(base + poff0, 0, pbytes, stream);

  const int egrid = N_EDGESC / 256;            // 3125
  const int ggrid = (N_NODESC + BMR - 1) / BMR;  // 1563
  const int agrid = (N_NODESC + 3) / 4;          // 12500
  const int pgrid = (N_NODESC + 63) / 64;        // 782

  for (int side = 0; side < 2; ++side) {
    const float* x = side ? xB : xA;
    const int* ei = side ? eiB : eiA;
    const int* bat = side ? batB : batA;
    const float* W1 = side ? WB1 : WA1;
    const float* b1 = side ? bB1 : bA1;
    const float* W2 = side ? WB2 : WA2;
    const float* b2 = side ? bB2 : bA2;
    float* ps = side ? psB : psA;
    int* pc = side ? pcB : pcA;

    hipMemsetAsync(base + zoff0, 0, zbytes, stream);
    count_kernel<<<egrid, 256, 0, stream>>>(ei, cnt);
    degsum_kernel<<<SCAN_G, 256, 0, stream>>>(cnt, inv, bsum);
    scanb_kernel<<<1, 256, 0, stream>>>(bsum, bbase);
    rowptr_kernel<<<SCAN_G, 256, 0, stream>>>(cnt, bbase, rowptr);
    fill_kernel<<<egrid, 256, 0, stream>>>(ei, rowptr, fillc, csr);
    gemm_enc<<<ggrid, 256, 0, stream>>>(x, W1, inv, h_buf);
    agg_kernel<<<agrid, 256, 0, stream>>>(h_buf, inv, rowptr, csr, b1, g_buf, 1);
    gemm_enc<<<ggrid, 256, 0, stream>>>(g_buf, W2, inv, h_buf);
    agg_kernel<<<agrid, 256, 0, stream>>>(h_buf, inv, rowptr, csr, b2, g_buf, 0);
    pool_kernel<<<pgrid, 128, 0, stream>>>(g_buf, bat, ps, pc);
  }

  mean_kernel<<<128, 128, 0, stream>>>(psA, pcA, psB, pcB, mhA, mhB);
  qkv_kernel<<<384, 128, 0, stream>>>(mhA, mhB, Wq, bq, Wk, bk, Wv, bv, Q0, K0, V0, Q1, K1, V1);
  attn_kernel<<<512, 64, 0, stream>>>(Q0, K0, V0, Q1, K1, V1, O0, O1);
  oln_kernel<<<128, 128, 0, stream>>>(O0, O1, mhA, mhB, Wo, bo, g1, be1, X0, X1);
  ff1_kernel<<<128, 256, 0, stream>>>(X0, X1, Wf1, bf1, F0, F1);
  ffln_kernel<<<128, 128, 0, stream>>>(F0, F1, X0, X1, Wf2, bf2, g2, be2, Y0, Y1);
  head_kernel<<<64, 128, 0, stream>>>(Y0, Y1, Wl1, bl1, Wl2, bl2, (float*)d_out);
}

// Round 6
// 426.293 us; speedup vs baseline: 4.9385x; 1.2463x over previous
//
#include <hip/hip_runtime.h>

#define N_NODESC 50000
#define N_EDGESC 800000
#define DIMC 128
#define NGC 64
#define HDC 32
#define SLOPEF 0.01f
#define EPSF 1e-5f
#define SCALEF 0.17677669529663687f  // 32^-0.5

#define NBUK 782   // ceil(50000/64) buckets of 64 dst nodes
#define KBLK 50    // binning blocks
#define EPB 16000  // edges per binning block (50*16000 = 800000)

// fp32 <-> bf16 (RNE)
static __device__ __forceinline__ unsigned short f2bf(float f) {
  unsigned u = __float_as_uint(f);
  u = u + 0x7FFFu + ((u >> 16) & 1u);
  return (unsigned short)(u >> 16);
}
static __device__ __forceinline__ float bf2f(unsigned short h) {
  return __uint_as_float(((unsigned)h) << 16);
}

// ---------------- CSR build: locality-preserving two-level counting sort ----------------
// hist[blk*NBUK + b] = # edges of block blk with dst in bucket b
__global__ __launch_bounds__(1024) void kbhist(const int* __restrict__ ei, int* __restrict__ hist) {
  __shared__ int lh[NBUK];
  int t = threadIdx.x;
  for (int i = t; i < NBUK; i += 1024) lh[i] = 0;
  __syncthreads();
  int e0 = blockIdx.x * EPB;
  for (int e = e0 + t; e < e0 + EPB; e += 1024) {
    int d = ei[N_EDGESC + e];
    atomicAdd(&lh[d >> 6], 1);
  }
  __syncthreads();
  for (int i = t; i < NBUK; i += 1024) hist[blockIdx.x * NBUK + i] = lh[i];
}

// bucket totals + exclusive scan -> per-(block,bucket) bases, bucket bases
__global__ __launch_bounds__(1024) void kbscan(const int* __restrict__ hist, int* __restrict__ bbase,
                                               int* __restrict__ bucket_base) {
  __shared__ int sd[1024];
  int t = threadIdx.x;
  int tot = 0;
  if (t < NBUK) {
    for (int k = 0; k < KBLK; ++k) tot += hist[k * NBUK + t];
  }
  sd[t] = tot;
  __syncthreads();
  for (int off = 1; off < 1024; off <<= 1) {
    int u = (t >= off) ? sd[t - off] : 0;
    __syncthreads();
    sd[t] += u;
    __syncthreads();
  }
  if (t < NBUK) {
    int run = sd[t] - tot;  // exclusive bucket base
    bucket_base[t] = run;
    for (int k = 0; k < KBLK; ++k) {
      bbase[k * NBUK + t] = run;
      run += hist[k * NBUK + t];
    }
  }
  if (t == 0) bucket_base[NBUK] = N_EDGESC;
}

// scatter edges into bucket-major order; each (block,bucket) slice is block-exclusive
__global__ __launch_bounds__(1024) void kbin(const int* __restrict__ ei, const int* __restrict__ bbase,
                                             unsigned* __restrict__ packed) {
  __shared__ int cur[NBUK];
  int t = threadIdx.x;
  for (int i = t; i < NBUK; i += 1024) cur[i] = bbase[blockIdx.x * NBUK + i];
  __syncthreads();
  int e0 = blockIdx.x * EPB;
  for (int e = e0 + t; e < e0 + EPB; e += 1024) {
    int s = ei[e];
    int d = ei[N_EDGESC + e];
    int b = d >> 6;
    int pos = atomicAdd(&cur[b], 1);
    packed[pos] = (unsigned)s | ((unsigned)(d & 63) << 16);
  }
}

// per-bucket counting sort by local node; emits csr16, rowptr, inv
__global__ __launch_bounds__(256) void kcsr(const unsigned* __restrict__ packed, const int* __restrict__ bucket_base,
                                            unsigned short* __restrict__ csr16, int* __restrict__ rowptr,
                                            float* __restrict__ inv) {
  __shared__ int h64[64], o64[64], c64[64];
  int b = blockIdx.x, t = threadIdx.x;
  int beg = bucket_base[b], end = bucket_base[b + 1];
  if (t < 64) h64[t] = 0;
  __syncthreads();
  for (int e = beg + t; e < end; e += 256) atomicAdd(&h64[packed[e] >> 16], 1);
  __syncthreads();
  if (t == 0) {
    int run = 0;
    for (int j = 0; j < 64; ++j) { o64[j] = run; run += h64[j]; }
  }
  __syncthreads();
  if (t < 64) c64[t] = o64[t];
  __syncthreads();
  for (int e = beg + t; e < end; e += 256) {
    unsigned p = packed[e];
    int pos = atomicAdd(&c64[p >> 16], 1);
    csr16[beg + pos] = (unsigned short)(p & 0xFFFFu);
  }
  if (t < 64) {
    int node = b * 64 + t;
    if (node < N_NODESC) {
      rowptr[node] = beg + o64[t];
      inv[node] = rsqrtf((float)h64[t] + 1.0f);
    }
  }
  if (b == NBUK - 1 && t == 0) rowptr[N_NODESC] = N_EDGESC;
}

// ---------------- encoder GEMM: Y(bf16) = (X @ W) * inv[row] ----------------
#define BMR 32
__global__ __launch_bounds__(256, 2) void gemm_enc(const float* __restrict__ X, const float* __restrict__ W,
                                                   const float* __restrict__ inv, unsigned short* __restrict__ Y) {
  __shared__ float Ws[DIMC * DIMC];   // 64 KB
  __shared__ float Xs[BMR * DIMC];    // 16 KB
  int t = threadIdx.x;
  int row0 = blockIdx.x * BMR;
#pragma unroll
  for (int i = 0; i < DIMC * DIMC; i += 1024) {
    *(float4*)&Ws[i + t * 4] = *(const float4*)&W[i + t * 4];
  }
  {
    const size_t lim = (size_t)N_NODESC * DIMC;
#pragma unroll
    for (int i = 0; i < BMR * DIMC; i += 1024) {
      int li = i + t * 4;
      size_t gi = (size_t)row0 * DIMC + li;
      float4 v = make_float4(0.f, 0.f, 0.f, 0.f);
      if (gi < lim) v = *(const float4*)&X[gi];
      *(float4*)&Xs[li] = v;
    }
  }
  __syncthreads();
  const int cg = (t & 31) * 4;   // col base (4 cols)
  const int rg = (t >> 5) * 4;   // row base (4 rows)
  float acc[4][4];
#pragma unroll
  for (int i = 0; i < 4; ++i)
#pragma unroll
    for (int j = 0; j < 4; ++j) acc[i][j] = 0.f;
  for (int k0 = 0; k0 < DIMC; k0 += 4) {
    float4 xv[4], wv[4];
#pragma unroll
    for (int i = 0; i < 4; ++i) xv[i] = *(const float4*)&Xs[(rg + i) * DIMC + k0];
#pragma unroll
    for (int kk = 0; kk < 4; ++kk) wv[kk] = *(const float4*)&Ws[(k0 + kk) * DIMC + cg];
#pragma unroll
    for (int i = 0; i < 4; ++i) {
      const float* xp = (const float*)&xv[i];
#pragma unroll
      for (int kk = 0; kk < 4; ++kk) {
        float xs = xp[kk];
        acc[i][0] += xs * wv[kk].x;
        acc[i][1] += xs * wv[kk].y;
        acc[i][2] += xs * wv[kk].z;
        acc[i][3] += xs * wv[kk].w;
      }
    }
  }
#pragma unroll
  for (int i = 0; i < 4; ++i) {
    int r = row0 + rg + i;
    if (r < N_NODESC) {
      float s = inv[r];
      ushort4 o;
      o.x = f2bf(acc[i][0] * s);
      o.y = f2bf(acc[i][1] * s);
      o.z = f2bf(acc[i][2] * s);
      o.w = f2bf(acc[i][3] * s);
      *(ushort4*)&Y[(size_t)r * DIMC + cg] = o;
    }
  }
}

// ---------------- aggregation: out = (sum_{src} Hs[src] + Hs[i]) * inv[i] + b ----------------
// Hs bf16 (256B rows); one wave per node; lane = (colgroup, edge-slot); ushort4 gathers.
__global__ __launch_bounds__(256) void agg_kernel(const unsigned short* __restrict__ Hs, const float* __restrict__ inv,
                                                  const int* __restrict__ rowptr, const unsigned short* __restrict__ csr,
                                                  const float* __restrict__ bias, float* __restrict__ out,
                                                  int do_relu) {
  int node = blockIdx.x * 4 + (threadIdx.x >> 6);
  if (node >= N_NODESC) return;
  int lane = threadIdx.x & 63;
  int cg = (lane & 31) * 4;
  int slot = lane >> 5;
  int beg = rowptr[node], end = rowptr[node + 1];
  float4 acc = make_float4(0.f, 0.f, 0.f, 0.f);
  int e = beg;
  for (; e + 8 <= end; e += 8) {  // 8 edges/iter: 4 per slot, 4 gathers in flight
    int s0 = csr[e + slot];
    int s1 = csr[e + 2 + slot];
    int s2 = csr[e + 4 + slot];
    int s3 = csr[e + 6 + slot];
    ushort4 v0 = *(const ushort4*)&Hs[(size_t)s0 * DIMC + cg];
    ushort4 v1 = *(const ushort4*)&Hs[(size_t)s1 * DIMC + cg];
    ushort4 v2 = *(const ushort4*)&Hs[(size_t)s2 * DIMC + cg];
    ushort4 v3 = *(const ushort4*)&Hs[(size_t)s3 * DIMC + cg];
    acc.x += (bf2f(v0.x) + bf2f(v1.x)) + (bf2f(v2.x) + bf2f(v3.x));
    acc.y += (bf2f(v0.y) + bf2f(v1.y)) + (bf2f(v2.y) + bf2f(v3.y));
    acc.z += (bf2f(v0.z) + bf2f(v1.z)) + (bf2f(v2.z) + bf2f(v3.z));
    acc.w += (bf2f(v0.w) + bf2f(v1.w)) + (bf2f(v2.w) + bf2f(v3.w));
  }
  for (int t = e + slot; t < end; t += 2) {
    int s = csr[t];
    ushort4 v = *(const ushort4*)&Hs[(size_t)s * DIMC + cg];
    acc.x += bf2f(v.x); acc.y += bf2f(v.y); acc.z += bf2f(v.z); acc.w += bf2f(v.w);
  }
  acc.x += __shfl_xor(acc.x, 32, 64);
  acc.y += __shfl_xor(acc.y, 32, 64);
  acc.z += __shfl_xor(acc.z, 32, 64);
  acc.w += __shfl_xor(acc.w, 32, 64);
  if (slot == 0) {
    ushort4 sv = *(const ushort4*)&Hs[(size_t)node * DIMC + cg];
    float sc = inv[node];
    float4 b = *(const float4*)&bias[cg];
    float4 o;
    o.x = (acc.x + bf2f(sv.x)) * sc + b.x;
    o.y = (acc.y + bf2f(sv.y)) * sc + b.y;
    o.z = (acc.z + bf2f(sv.z)) * sc + b.z;
    o.w = (acc.w + bf2f(sv.w)) * sc + b.w;
    if (do_relu) {
      o.x = (o.x > 0.f) ? o.x : SLOPEF * o.x;
      o.y = (o.y > 0.f) ? o.y : SLOPEF * o.y;
      o.z = (o.z > 0.f) ? o.z : SLOPEF * o.z;
      o.w = (o.w > 0.f) ? o.w : SLOPEF * o.w;
    }
    *(float4*)&out[(size_t)node * DIMC + cg] = o;
  }
}

// ---------------- pooling ----------------
__global__ __launch_bounds__(128) void pool_kernel(const float* __restrict__ G, const int* __restrict__ batch,
                                                   float* __restrict__ psum, int* __restrict__ pcnt) {
  int t = threadIdx.x;
  int n0 = blockIdx.x * 64;
  int nend = min(n0 + 64, N_NODESC);
  int cur = batch[n0];
  float acc = 0.f;
  int c = 0;
  for (int n = n0; n < nend; ++n) {
    int b = batch[n];
    if (b != cur) {
      atomicAdd(&psum[cur * DIMC + t], acc);
      if (t == 0) atomicAdd(&pcnt[cur], c);
      acc = 0.f;
      c = 0;
      cur = b;
    }
    acc += G[(size_t)n * DIMC + t];
    c += 1;
  }
  atomicAdd(&psum[cur * DIMC + t], acc);
  if (t == 0) atomicAdd(&pcnt[cur], c);
}

__global__ __launch_bounds__(128) void mean_kernel(const float* __restrict__ psA, const int* __restrict__ pcA,
                                                   const float* __restrict__ psB, const int* __restrict__ pcB,
                                                   float* __restrict__ hA, float* __restrict__ hB) {
  int dir = blockIdx.x >> 6, g = blockIdx.x & 63, t = threadIdx.x;
  const float* ps = dir ? psB : psA;
  const int* pc = dir ? pcB : pcA;
  float* h = dir ? hB : hA;
  h[g * DIMC + t] = ps[g * DIMC + t] / (float)max(pc[g], 1);
}

// ---------------- attention (64 tokens per side) ----------------
__global__ __launch_bounds__(128) void qkv_kernel(const float* __restrict__ hA, const float* __restrict__ hB,
                                                  const float* __restrict__ Wq, const float* __restrict__ bq,
                                                  const float* __restrict__ Wk, const float* __restrict__ bk,
                                                  const float* __restrict__ Wv, const float* __restrict__ bv,
                                                  float* __restrict__ Q0, float* __restrict__ K0, float* __restrict__ V0,
                                                  float* __restrict__ Q1, float* __restrict__ K1, float* __restrict__ V1) {
  __shared__ float xs[DIMC];
  int task = blockIdx.x >> 6, r = blockIdx.x & 63, t = threadIdx.x;
  const float *X, *W, *b;
  float* Y;
  switch (task) {
    case 0: X = hA; W = Wq; b = bq; Y = Q0; break;
    case 1: X = hB; W = Wk; b = bk; Y = K0; break;
    case 2: X = hB; W = Wv; b = bv; Y = V0; break;
    case 3: X = hB; W = Wq; b = bq; Y = Q1; break;
    case 4: X = hA; W = Wk; b = bk; Y = K1; break;
    default: X = hA; W = Wv; b = bv; Y = V1; break;
  }
  xs[t] = X[r * DIMC + t];
  __syncthreads();
  float acc = b[t];
  for (int k = 0; k < DIMC; ++k) acc += xs[k] * W[k * DIMC + t];
  Y[r * DIMC + t] = acc;
}

__global__ __launch_bounds__(64) void attn_kernel(const float* __restrict__ Q0, const float* __restrict__ K0,
                                                  const float* __restrict__ V0, const float* __restrict__ Q1,
                                                  const float* __restrict__ K1, const float* __restrict__ V1,
                                                  float* __restrict__ O0, float* __restrict__ O1) {
  __shared__ float ps[64];
  int b = blockIdx.x;
  int dir = b >> 8, h = (b >> 6) & 3, q = b & 63;
  const float* Q = dir ? Q1 : Q0;
  const float* K = dir ? K1 : K0;
  const float* V = dir ? V1 : V0;
  float* O = dir ? O1 : O0;
  int k = threadIdx.x;
  const float* qp = Q + q * DIMC + h * HDC;
  const float* kp = K + k * DIMC + h * HDC;
  float s = 0.f;
#pragma unroll
  for (int d = 0; d < HDC; ++d) s += qp[d] * kp[d];
  s *= SCALEF;
  float m = s;
#pragma unroll
  for (int off = 32; off >= 1; off >>= 1) m = fmaxf(m, __shfl_xor(m, off, 64));
  float p = __expf(s - m);
  float sum = p;
#pragma unroll
  for (int off = 32; off >= 1; off >>= 1) sum += __shfl_xor(sum, off, 64);
  p /= sum;
  ps[k] = p;
  __syncthreads();
  int half = k >> 5, d = k & 31;
  float acc = 0.f;
#pragma unroll
  for (int j = 0; j < 32; ++j) {
    int kk = half * 32 + j;
    acc += ps[kk] * V[kk * DIMC + h * HDC + d];
  }
  acc += __shfl_xor(acc, 32, 64);
  if (half == 0) O[q * DIMC + h * HDC + d] = acc;
}

__device__ inline float blk_sum128(float v, float* red) {
#pragma unroll
  for (int off = 32; off >= 1; off >>= 1) v += __shfl_xor(v, off, 64);
  if ((threadIdx.x & 63) == 0) red[threadIdx.x >> 6] = v;
  __syncthreads();
  float r = red[0] + red[1];
  __syncthreads();
  return r;
}

__global__ __launch_bounds__(128) void oln_kernel(const float* __restrict__ O0, const float* __restrict__ O1,
                                                  const float* __restrict__ hA, const float* __restrict__ hB,
                                                  const float* __restrict__ Wo, const float* __restrict__ bo,
                                                  const float* __restrict__ g1, const float* __restrict__ be1,
                                                  float* __restrict__ X0, float* __restrict__ X1) {
  __shared__ float os[DIMC];
  __shared__ float red[2];
  int dir = blockIdx.x >> 6, q = blockIdx.x & 63, t = threadIdx.x;
  const float* O = dir ? O1 : O0;
  const float* xq = dir ? hB : hA;
  float* Xo = dir ? X1 : X0;
  os[t] = O[q * DIMC + t];
  __syncthreads();
  float acc = bo[t] + xq[q * DIMC + t];
  for (int k = 0; k < DIMC; ++k) acc += os[k] * Wo[k * DIMC + t];
  float mean = blk_sum128(acc, red) * (1.f / DIMC);
  float d = acc - mean;
  float var = blk_sum128(d * d, red) * (1.f / DIMC);
  Xo[q * DIMC + t] = d * rsqrtf(var + EPSF) * g1[t] + be1[t];
}

__global__ __launch_bounds__(256) void ff1_kernel(const float* __restrict__ X0, const float* __restrict__ X1,
                                                  const float* __restrict__ Wf1, const float* __restrict__ bf1,
                                                  float* __restrict__ F0, float* __restrict__ F1) {
  __shared__ float xs[DIMC];
  int dir = blockIdx.x >> 6, q = blockIdx.x & 63, t = threadIdx.x;
  const float* X = dir ? X1 : X0;
  float* F = dir ? F1 : F0;
  if (t < DIMC) xs[t] = X[q * DIMC + t];
  __syncthreads();
  float acc = bf1[t];
  for (int k = 0; k < DIMC; ++k) acc += xs[k] * Wf1[k * 256 + t];
  acc = (acc > 0.f) ? acc : SLOPEF * acc;
  F[q * 256 + t] = acc;
}

__global__ __launch_bounds__(128) void ffln_kernel(const float* __restrict__ F0, const float* __restrict__ F1,
                                                   const float* __restrict__ X0, const float* __restrict__ X1,
                                                   const float* __restrict__ Wf2, const float* __restrict__ bf2,
                                                   const float* __restrict__ g2, const float* __restrict__ be2,
                                                   float* __restrict__ Y0, float* __restrict__ Y1) {
  __shared__ float fs[256];
  __shared__ float red[2];
  int dir = blockIdx.x >> 6, q = blockIdx.x & 63, t = threadIdx.x;
  const float* F = dir ? F1 : F0;
  const float* X = dir ? X1 : X0;
  float* Y = dir ? Y1 : Y0;
  fs[t] = F[q * 256 + t];
  fs[t + 128] = F[q * 256 + t + 128];
  __syncthreads();
  float acc = bf2[t] + X[q * DIMC + t];
  for (int k = 0; k < 256; ++k) acc += fs[k] * Wf2[k * DIMC + t];
  float mean = blk_sum128(acc, red) * (1.f / DIMC);
  float d = acc - mean;
  float var = blk_sum128(d * d, red) * (1.f / DIMC);
  Y[q * DIMC + t] = d * rsqrtf(var + EPSF) * g2[t] + be2[t];
}

__global__ __launch_bounds__(128) void head_kernel(const float* __restrict__ Y0, const float* __restrict__ Y1,
                                                   const float* __restrict__ Wl1, const float* __restrict__ bl1,
                                                   const float* __restrict__ Wl2, const float* __restrict__ bl2,
                                                   float* __restrict__ out) {
  __shared__ float cs[256];
  __shared__ float red[2];
  int g = blockIdx.x, t = threadIdx.x;
  cs[t] = Y0[g * DIMC + t];
  cs[t + 128] = Y1[g * DIMC + t];
  __syncthreads();
  float acc = bl1[t];
  for (int k = 0; k < 256; ++k) acc += cs[k] * Wl1[k * DIMC + t];
  acc = fmaxf(acc, 0.f);
  float s = blk_sum128(acc * Wl2[t], red);
  if (t == 0) out[g] = s + bl2[0];
}

// ---------------- host ----------------
extern "C" void kernel_launch(void* const* d_in, const int* in_sizes, int n_in,
                              void* d_out, int out_size, void* d_ws, size_t ws_size,
                              hipStream_t stream) {
  const float* xA = (const float*)d_in[0];
  const float* xB = (const float*)d_in[1];
  const int* eiA = (const int*)d_in[2];
  const int* eiB = (const int*)d_in[3];
  const int* batA = (const int*)d_in[4];
  const int* batB = (const int*)d_in[5];
  const float* WA1 = (const float*)d_in[6];
  const float* WA2 = (const float*)d_in[7];
  const float* WB1 = (const float*)d_in[8];
  const float* WB2 = (const float*)d_in[9];
  const float* Wq = (const float*)d_in[10];
  const float* Wk = (const float*)d_in[11];
  const float* Wv = (const float*)d_in[12];
  const float* Wo = (const float*)d_in[13];
  const float* Wf1 = (const float*)d_in[14];
  const float* Wf2 = (const float*)d_in[15];
  const float* Wl1 = (const float*)d_in[16];
  const float* Wl2 = (const float*)d_in[17];
  const float* bA1 = (const float*)d_in[18];
  const float* bA2 = (const float*)d_in[19];
  const float* bB1 = (const float*)d_in[20];
  const float* bB2 = (const float*)d_in[21];
  const float* bq = (const float*)d_in[22];
  const float* bk = (const float*)d_in[23];
  const float* bv = (const float*)d_in[24];
  const float* bo = (const float*)d_in[25];
  const float* bf1 = (const float*)d_in[26];
  const float* bf2 = (const float*)d_in[27];
  const float* bl1 = (const float*)d_in[28];
  const float* bl2 = (const float*)d_in[29];
  const float* g1 = (const float*)d_in[30];
  const float* be1 = (const float*)d_in[31];
  const float* g2 = (const float*)d_in[32];
  const float* be2 = (const float*)d_in[33];

  char* base = (char*)d_ws;
  size_t off = 0;
  auto alloc = [&](size_t bytes) -> char* {
    char* r = base + off;
    off += (bytes + 255) & ~(size_t)255;
    return r;
  };
  unsigned short* h_buf = (unsigned short*)alloc((size_t)N_NODESC * DIMC * 2);  // bf16
  float* g_buf = (float*)alloc((size_t)N_NODESC * DIMC * 4);
  unsigned* packed = (unsigned*)alloc((size_t)N_EDGESC * 4);
  unsigned short* csr16 = (unsigned short*)alloc((size_t)N_EDGESC * 2);
  int* rowptr = (int*)alloc((size_t)(N_NODESC + 1) * 4);
  float* inv = (float*)alloc((size_t)N_NODESC * 4);
  int* hist = (int*)alloc((size_t)KBLK * NBUK * 4);
  int* bbase = (int*)alloc((size_t)KBLK * NBUK * 4);
  int* bucket_base = (int*)alloc((size_t)(NBUK + 1) * 4);
  size_t poff0 = off;
  float* psA = (float*)alloc(NGC * DIMC * 4);
  float* psB = (float*)alloc(NGC * DIMC * 4);
  int* pcA = (int*)alloc(NGC * 4);
  int* pcB = (int*)alloc(NGC * 4);
  size_t pbytes = off - poff0;  // pool region (zeroed once per call)
  float* mhA = (float*)alloc(NGC * DIMC * 4);
  float* mhB = (float*)alloc(NGC * DIMC * 4);
  float* Q0 = (float*)alloc(NGC * DIMC * 4);
  float* K0 = (float*)alloc(NGC * DIMC * 4);
  float* V0 = (float*)alloc(NGC * DIMC * 4);
  float* Q1 = (float*)alloc(NGC * DIMC * 4);
  float* K1 = (float*)alloc(NGC * DIMC * 4);
  float* V1 = (float*)alloc(NGC * DIMC * 4);
  float* O0 = (float*)alloc(NGC * DIMC * 4);
  float* O1 = (float*)alloc(NGC * DIMC * 4);
  float* X0 = (float*)alloc(NGC * DIMC * 4);
  float* X1 = (float*)alloc(NGC * DIMC * 4);
  float* F0 = (float*)alloc(NGC * 256 * 4);
  float* F1 = (float*)alloc(NGC * 256 * 4);
  float* Y0 = (float*)alloc(NGC * DIMC * 4);
  float* Y1 = (float*)alloc(NGC * DIMC * 4);

  hipMemsetAsync(base + poff0, 0, pbytes, stream);

  const int ggrid = (N_NODESC + BMR - 1) / BMR;  // 1563
  const int agrid = (N_NODESC + 3) / 4;          // 12500
  const int pgrid = (N_NODESC + 63) / 64;        // 782

  for (int side = 0; side < 2; ++side) {
    const float* x = side ? xB : xA;
    const int* ei = side ? eiB : eiA;
    const int* bat = side ? batB : batA;
    const float* W1 = side ? WB1 : WA1;
    const float* b1 = side ? bB1 : bA1;
    const float* W2 = side ? WB2 : WA2;
    const float* b2 = side ? bB2 : bA2;
    float* ps = side ? psB : psA;
    int* pc = side ? pcB : pcA;

    kbhist<<<KBLK, 1024, 0, stream>>>(ei, hist);
    kbscan<<<1, 1024, 0, stream>>>(hist, bbase, bucket_base);
    kbin<<<KBLK, 1024, 0, stream>>>(ei, bbase, packed);
    kcsr<<<NBUK, 256, 0, stream>>>(packed, bucket_base, csr16, rowptr, inv);
    gemm_enc<<<ggrid, 256, 0, stream>>>(x, W1, inv, h_buf);
    agg_kernel<<<agrid, 256, 0, stream>>>(h_buf, inv, rowptr, csr16, b1, g_buf, 1);
    gemm_enc<<<ggrid, 256, 0, stream>>>(g_buf, W2, inv, h_buf);
    agg_kernel<<<agrid, 256, 0, stream>>>(h_buf, inv, rowptr, csr16, b2, g_buf, 0);
    pool_kernel<<<pgrid, 128, 0, stream>>>(g_buf, bat, ps, pc);
  }

  mean_kernel<<<128, 128, 0, stream>>>(psA, pcA, psB, pcB, mhA, mhB);
  qkv_kernel<<<384, 128, 0, stream>>>(mhA, mhB, Wq, bq, Wk, bk, Wv, bv, Q0, K0, V0, Q1, K1, V1);
  attn_kernel<<<512, 64, 0, stream>>>(Q0, K0, V0, Q1, K1, V1, O0, O1);
  oln_kernel<<<128, 128, 0, stream>>>(O0, O1, mhA, mhB, Wo, bo, g1, be1, X0, X1);
  ff1_kernel<<<128, 256, 0, stream>>>(X0, X1, Wf1, bf1, F0, F1);
  ffln_kernel<<<128, 128, 0, stream>>>(F0, F1, X0, X1, Wf2, bf2, g2, be2, Y0, Y1);
  head_kernel<<<64, 128, 0, stream>>>(Y0, Y1, Wl1, bl1, Wl2, bl2, (float*)d_out);
}